// Round 8
// baseline (408.889 us; speedup 1.0000x reference)
//
#include <hip/hip_runtime.h>
#include <math.h>

#define Lh 2304
#define Ch 768
#define NHh 12
#define Bh 2
#define QS2 3072  // row stride of packed qkv activation buffer [qg|kg|ql|kl]

typedef unsigned short ushort_t;
typedef unsigned int uint_t;
typedef __attribute__((ext_vector_type(8))) short bf16x8;
typedef __attribute__((ext_vector_type(4))) float f32x4;
typedef __attribute__((ext_vector_type(16))) float f32x16;
#define MFMA16(a, b, c) __builtin_amdgcn_mfma_f32_16x16x32_bf16(a, b, c, 0, 0, 0)
#define MFMA32(a, b, c) __builtin_amdgcn_mfma_f32_32x32x16_bf16(a, b, c, 0, 0, 0)

// softmax in exp2 domain: exp(s*0.125 + m) == exp2(s*SCL2 + m*log2e)  (R1-validated)
#define SCL2 0.18033688f        // 0.125 * log2(e)
#define MSK2 1.4426950e9f       // 1e9  * log2(e)
#if __has_builtin(__builtin_amdgcn_exp2f)
#define EXP2F(x) __builtin_amdgcn_exp2f(x)
#else
#define EXP2F(x) exp2f(x)
#endif

__device__ __forceinline__ ushort_t f2bf(float f) {
    union { float f; uint_t u; } v; v.f = f;
    uint_t u = v.u + 0x7fffu + ((v.u >> 16) & 1u);   // RNE
    return (ushort_t)(u >> 16);
}
// pack 2 fp32 -> 2 bf16 (RNE) into one u32
__device__ __forceinline__ uint_t pack2bf(float a, float b) {
    return (uint_t)f2bf(a) | ((uint_t)f2bf(b) << 16);
}
// packed f32->bf16 pair (T12; no builtin on gfx950)
__device__ __forceinline__ uint_t cvtpk(float lo, float hi) {
    uint_t r;
    asm("v_cvt_pk_bf16_f32 %0, %1, %2" : "=v"(r) : "v"(lo), "v"(hi));
    return r;
}
// exchange a's upper 32 lanes with b's lower 32 lanes (both outputs usable)
__device__ __forceinline__ void plswap(uint_t& a, uint_t& b) {
    asm volatile("v_permlane32_swap_b32 %0, %1" : "+v"(a), "+v"(b));
}

// async global->LDS, 16B/lane, dest = wave-uniform base + lane*16
__device__ __forceinline__ void llds16(ushort_t* dst, const ushort_t* src) {
    __builtin_amdgcn_global_load_lds(
        (__attribute__((address_space(1))) void*)(const_cast<ushort_t*>(src)),
        (__attribute__((address_space(3))) void*)dst, 16, 0, 0);
}

// ---------------------------------------------------------------- layernorm (fp32 in, bf16 out)
__device__ __forceinline__ void ln_body(const float* __restrict__ x, const float* __restrict__ w,
                                        const float* __restrict__ b, ushort_t* __restrict__ y,
                                        int row, float* red)
{
    int tid = threadIdx.x;
    const float* xr = x + (size_t)row * Ch;
    float v0 = xr[tid], v1 = xr[tid + 256], v2 = xr[tid + 512];
    red[tid] = v0 + v1 + v2;
    __syncthreads();
    for (int st = 128; st > 0; st >>= 1) {
        if (tid < st) red[tid] += red[tid + st];
        __syncthreads();
    }
    float mean = red[0] * (1.0f / 768.0f);
    __syncthreads();
    float d0 = v0 - mean, d1 = v1 - mean, d2 = v2 - mean;
    red[tid] = d0 * d0 + d1 * d1 + d2 * d2;
    __syncthreads();
    for (int st = 128; st > 0; st >>= 1) {
        if (tid < st) red[tid] += red[tid + st];
        __syncthreads();
    }
    float rstd = rsqrtf(red[0] * (1.0f / 768.0f) + 1e-6f);
    ushort_t* yr = y + (size_t)row * Ch;
    yr[tid]       = f2bf(d0 * rstd * w[tid]       + b[tid]);
    yr[tid + 256] = f2bf(d1 * rstd * w[tid + 256] + b[tid + 256]);
    yr[tid + 512] = f2bf(d2 * rstd * w[tid + 512] + b[tid + 512]);
}

__global__ __launch_bounds__(256)
void layernorm_bf16_kernel(const float* __restrict__ x, const float* __restrict__ w,
                           const float* __restrict__ b, ushort_t* __restrict__ y)
{
    __shared__ float red[256];
    ln_body(x, w, b, y, blockIdx.x, red);
}

// ln1 + mask fused into one dispatch (block-uniform branch)
__global__ __launch_bounds__(256)
void ln_mask_kernel(const float* __restrict__ x, const float* __restrict__ w,
                    const float* __restrict__ b, ushort_t* __restrict__ y,
                    const float* __restrict__ mask, float* __restrict__ fg,
                    float* __restrict__ bgw)
{
    __shared__ float red[256];
    int bid = blockIdx.x;
    if (bid < 4608) {
        ln_body(x, w, b, y, bid, red);
        return;
    }
    int win = bid - 4608;            // 0..71
    int tid = threadIdx.x;
    if (tid >= 64) return;
    int bb = win / 36, ww = win % 36;
    int wi = ww / 6, wj = ww % 6;
    int i = wi * 8 + (tid >> 3), j = wj * 8 + (tid & 7);
    const float* mb = mask + (size_t)bb * 192 * 192 + (size_t)(i * 4) * 192 + j * 4;
    float s = 0.0f;
    #pragma unroll
    for (int di = 0; di < 4; ++di) {
        float4 v = *(const float4*)(mb + (size_t)di * 192);
        s += v.x + v.y + v.z + v.w;
    }
    float f = (s * (1.0f / 16.0f) > 0.4f) ? 1.0f : 0.0f;
    fg[bb * Lh + i * 48 + j] = f;
    unsigned long long bg = __ballot(f == 0.0f);
    if (tid == 0) bgw[win] = bg ? 1.0f : 0.0f;
}

// ---------------------------------------------------------------- batched weight cast+transpose
// blocks 2304/2305 copy the qkv biases (replaces 2 hipMemcpyAsync launches)
__global__ __launch_bounds__(256)
void transpose_all_kernel(const float* __restrict__ w_qkv_g, const float* __restrict__ w_qkv_l,
                          const float* __restrict__ w_o_g, const float* __restrict__ w_o_l,
                          const float* __restrict__ w_fc1, const float* __restrict__ w_fc2,
                          const float* __restrict__ b_qkv_g, const float* __restrict__ b_qkv_l,
                          ushort_t* __restrict__ wtq, ushort_t* __restrict__ wt_o_g,
                          ushort_t* __restrict__ wt_o_l, ushort_t* __restrict__ wt_fc1,
                          ushort_t* __restrict__ wt_fc2, float* __restrict__ biasq)
{
    int blk = blockIdx.x;
    int tid = threadIdx.x;
    if (blk >= 2304) {
        int which = blk - 2304;
        const float* src = which ? b_qkv_l : b_qkv_g;
        float* dst = biasq + which * 2304;
        for (int i = tid; i < 2304; i += 256) dst[i] = src[i];
        return;
    }
    const float* W; ushort_t* D; int K, N, nx, bx;
    const size_t CC = (size_t)Ch * Ch;
    if (blk < 432)       { int t = blk / 144; bx = blk % 144;
                           W = w_qkv_g + t * CC; D = wtq + t * CC; K = 768; N = 768; nx = 12; }
    else if (blk < 864)  { int r = blk - 432; int t = r / 144; bx = r % 144;
                           W = w_qkv_l + t * CC; D = wtq + (size_t)2304 * 768 + t * CC;
                           K = 768; N = 768; nx = 12; }
    else if (blk < 1008) { bx = blk - 864;  W = w_o_g; D = wt_o_g; K = 768; N = 768; nx = 12; }
    else if (blk < 1152) { bx = blk - 1008; W = w_o_l; D = wt_o_l; K = 768; N = 768; nx = 12; }
    else if (blk < 1728) { bx = blk - 1152; W = w_fc1; D = wt_fc1; K = 768; N = 3072; nx = 48; }
    else                 { bx = blk - 1728; W = w_fc2; D = wt_fc2; K = 3072; N = 768; nx = 12; }
    int n0 = (bx % nx) * 64;
    int k0 = (bx / nx) * 64;
    __shared__ float T[64][65];
    #pragma unroll
    for (int i = 0; i < 16; ++i) {
        int lin = i * 256 + tid;
        int r = lin >> 6, c = lin & 63;
        T[r][c] = W[(size_t)(k0 + r) * N + n0 + c];
    }
    __syncthreads();
    // vectorized: each unit = (n-row r, 4 consecutive k) -> one b64 store
    #pragma unroll
    for (int i = 0; i < 4; ++i) {
        int lin = i * 256 + tid;          // 0..1023
        int r = lin >> 4, c0 = (lin & 15) * 4;
        uint_t lo = pack2bf(T[c0][r], T[c0 + 1][r]);
        uint_t hi = pack2bf(T[c0 + 2][r], T[c0 + 3][r]);
        *(uint2*)&D[(size_t)(n0 + r) * K + k0 + c0] = make_uint2(lo, hi);
    }
}

// ---------------------------------------------------------------- bf16 MFMA GEMM (BM=128, BN template)
// flags: 1=gelu, 2=bf16 out, 4=qkv split-store (packed [qg|kg|ql|kl], stride 3072)
// VMODE template (R16): VMODE=1 = V column-tiles with unswapped MFMA ->
// acc lane = output col (d), quad*4+r = 4 consecutive tokens -> coalesced
// uint2 V^T stores. Dispatched separately (runtime branch broke pipelining, R5).
template<int BNt, int VMODE>
__global__ __launch_bounds__(256)
void gemm_bf16_t(const ushort_t* __restrict__ A, const ushort_t* __restrict__ Bt,
                 const float* __restrict__ bias, const float* __restrict__ residual,
                 void* __restrict__ C, ushort_t* __restrict__ vt,
                 int M, int N, int K, int flags)
{
    __shared__ ushort_t AsL[2][128 * 32];
    __shared__ ushort_t BsL[2][BNt * 32];
    int bm = blockIdx.y * 128;
    int bx = blockIdx.x;
    int bn;
    if (VMODE == 1) {
        bn = (bx < 6) ? 1536 + bx * 128 : 3840 + (bx - 6) * 128;   // V tiles
    } else if (flags & 4) {
        bn = (bx < 12) ? bx * 128 : 2304 + (bx - 12) * 128;        // Q|K tiles
    } else {
        bn = bx * BNt;
    }
    int tid = threadIdx.x;
    int lane = tid & 63;
    int wave = tid >> 6;
    int wm = wave >> 1, wn = wave & 1;
    int quad = lane >> 4, l15 = lane & 15;
    constexpr int NJ = BNt / 32;

    int srow = lane >> 2;
    int sg8 = ((lane & 3) ^ ((lane >> 3) & 3)) * 8;
    int fsw = (l15 >> 1) & 3;

    f32x4 acc[4][NJ];
    #pragma unroll
    for (int i = 0; i < 4; ++i)
        #pragma unroll
        for (int j = 0; j < NJ; ++j)
            acc[i][j] = (f32x4){0.f, 0.f, 0.f, 0.f};

    int iters = K / 32;
    llds16(&AsL[0][wave * 512], A + (size_t)(bm + wave * 16 + srow) * K + sg8);
    llds16(&AsL[0][(wave + 4) * 512], A + (size_t)(bm + (wave + 4) * 16 + srow) * K + sg8);
    llds16(&BsL[0][wave * 512], Bt + (size_t)(bn + wave * 16 + srow) * K + sg8);
    if (BNt == 128)
        llds16(&BsL[0][(wave + 4) * 512], Bt + (size_t)(bn + (wave + 4) * 16 + srow) * K + sg8);

    for (int kt = 0; kt < iters; ++kt) {
        int cur = kt & 1;
        __syncthreads();

        bf16x8 af[4], bfr[NJ];
        #pragma unroll
        for (int i = 0; i < 4; ++i)
            af[i] = *(const bf16x8*)&AsL[cur][(wm * 64 + i * 16 + l15) * 32 + ((quad ^ fsw) * 8)];
        #pragma unroll
        for (int j = 0; j < NJ; ++j)
            bfr[j] = *(const bf16x8*)&BsL[cur][(wn * (BNt / 2) + j * 16 + l15) * 32 + ((quad ^ fsw) * 8)];

        if (kt + 1 < iters) {
            int k0 = (kt + 1) * 32;
            int nxt = 1 - cur;
            llds16(&AsL[nxt][wave * 512], A + (size_t)(bm + wave * 16 + srow) * K + k0 + sg8);
            llds16(&AsL[nxt][(wave + 4) * 512], A + (size_t)(bm + (wave + 4) * 16 + srow) * K + k0 + sg8);
            llds16(&BsL[nxt][wave * 512], Bt + (size_t)(bn + wave * 16 + srow) * K + k0 + sg8);
            if (BNt == 128)
                llds16(&BsL[nxt][(wave + 4) * 512], Bt + (size_t)(bn + (wave + 4) * 16 + srow) * K + k0 + sg8);
        }

        if constexpr (VMODE == 0) {
            // swapped operands: lane = A row (output row), quad*4+r = B row (output col)
            #pragma unroll
            for (int i = 0; i < 4; ++i)
                #pragma unroll
                for (int j = 0; j < NJ; ++j)
                    acc[i][j] = MFMA16(bfr[j], af[i], acc[i][j]);
        } else {
            // unswapped: lane = B row (output col/d), quad*4+r = A row (token)
            #pragma unroll
            for (int i = 0; i < 4; ++i)
                #pragma unroll
                for (int j = 0; j < NJ; ++j)
                    acc[i][j] = MFMA16(af[i], bfr[j], acc[i][j]);
        }
    }

    if constexpr (VMODE == 1) {
        #pragma unroll
        for (int j = 0; j < NJ; ++j) {
            int col = bn + wn * (BNt / 2) + j * 16 + l15;
            int colp = col - ((col >= 3840) ? 3072 : 1536);
            float bc = bias[col];
            #pragma unroll
            for (int i = 0; i < 4; ++i) {
                int row0 = bm + wm * 64 + i * 16 + quad * 4;
                *(uint2*)&vt[(size_t)colp * 4608 + row0] =
                    make_uint2(pack2bf(acc[i][j][0] + bc, acc[i][j][1] + bc),
                               pack2bf(acc[i][j][2] + bc, acc[i][j][3] + bc));
            }
        }
        return;
    }

    #pragma unroll
    for (int i = 0; i < 4; ++i) {
        int row = bm + wm * 64 + i * 16 + l15;
        #pragma unroll
        for (int j = 0; j < NJ; ++j) {
            int col = bn + wn * (BNt / 2) + j * 16 + quad * 4;
            float4 bia = *(const float4*)&bias[col];
            float o0 = acc[i][j][0] + bia.x;
            float o1 = acc[i][j][1] + bia.y;
            float o2 = acc[i][j][2] + bia.z;
            float o3 = acc[i][j][3] + bia.w;
            if (flags & 1) {
                o0 = o0 * 0.5f * (1.0f + erff(o0 * 0.70710678f));
                o1 = o1 * 0.5f * (1.0f + erff(o1 * 0.70710678f));
                o2 = o2 * 0.5f * (1.0f + erff(o2 * 0.70710678f));
                o3 = o3 * 0.5f * (1.0f + erff(o3 * 0.70710678f));
            }
            if (residual) {
                float4 rs = *(const float4*)&residual[(size_t)row * N + col];
                o0 += rs.x; o1 += rs.y; o2 += rs.z; o3 += rs.w;
            }
            if (flags & 4) {
                int cq = col - ((col >= 2304) ? 768 : 0);
                *(uint2*)&((ushort_t*)C)[(size_t)row * QS2 + cq] =
                    make_uint2(pack2bf(o0, o1), pack2bf(o2, o3));
            } else if (flags & 2) {
                *(uint2*)&((ushort_t*)C)[(size_t)row * N + col] =
                    make_uint2(pack2bf(o0, o1), pack2bf(o2, o3));
            } else {
                *(float4*)&((float*)C)[(size_t)row * N + col] =
                    make_float4(o0, o1, o2, o3);
            }
        }
    }
}

// ---------------------------------------------------------------- dual o-projection
// single fused 24-kt loop staging all four tiles (Ag, Al, Bg, Bl) ->
// 16 MFMAs per barrier. LDS 48 KB.
__global__ __launch_bounds__(256)
void oproj_dual_kernel(const ushort_t* __restrict__ ctxg, const ushort_t* __restrict__ ctxl,
                       const ushort_t* __restrict__ Wg, const ushort_t* __restrict__ Wl,
                       const float* __restrict__ biasg, const float* __restrict__ biasl,
                       const float* __restrict__ x, float* __restrict__ x1,
                       const float* __restrict__ fg, const float* __restrict__ bgw)
{
    __shared__ ushort_t AgL[2][128 * 32];
    __shared__ ushort_t AlL[2][128 * 32];
    __shared__ ushort_t BgL[2][64 * 32];
    __shared__ ushort_t BlL[2][64 * 32];
    int bm = blockIdx.y * 128;
    int bn = blockIdx.x * 64;
    int tid = threadIdx.x;
    int lane = tid & 63;
    int wave = tid >> 6;
    int wm = wave >> 1, wn = wave & 1;
    int quad = lane >> 4, l15 = lane & 15;

    int srow = lane >> 2;
    int sg8 = ((lane & 3) ^ ((lane >> 3) & 3)) * 8;
    int fsw = (l15 >> 1) & 3;
    const int K = Ch, N = Ch, iters = Ch / 32;

    f32x4 accg[4][2], accl[4][2];
    #pragma unroll
    for (int i = 0; i < 4; ++i)
        #pragma unroll
        for (int j = 0; j < 2; ++j) {
            accg[i][j] = (f32x4){0.f, 0.f, 0.f, 0.f};
            accl[i][j] = (f32x4){0.f, 0.f, 0.f, 0.f};
        }

    llds16(&AgL[0][wave * 512], ctxg + (size_t)(bm + wave * 16 + srow) * K + sg8);
    llds16(&AgL[0][(wave + 4) * 512], ctxg + (size_t)(bm + (wave + 4) * 16 + srow) * K + sg8);
    llds16(&AlL[0][wave * 512], ctxl + (size_t)(bm + wave * 16 + srow) * K + sg8);
    llds16(&AlL[0][(wave + 4) * 512], ctxl + (size_t)(bm + (wave + 4) * 16 + srow) * K + sg8);
    llds16(&BgL[0][wave * 512], Wg + (size_t)(bn + wave * 16 + srow) * K + sg8);
    llds16(&BlL[0][wave * 512], Wl + (size_t)(bn + wave * 16 + srow) * K + sg8);

    for (int kt = 0; kt < iters; ++kt) {
        int cur = kt & 1;
        __syncthreads();
        bf16x8 afg[4], afl[4], bfg[2], bfl[2];
        #pragma unroll
        for (int i = 0; i < 4; ++i) {
            afg[i] = *(const bf16x8*)&AgL[cur][(wm * 64 + i * 16 + l15) * 32 + ((quad ^ fsw) * 8)];
            afl[i] = *(const bf16x8*)&AlL[cur][(wm * 64 + i * 16 + l15) * 32 + ((quad ^ fsw) * 8)];
        }
        #pragma unroll
        for (int j = 0; j < 2; ++j) {
            bfg[j] = *(const bf16x8*)&BgL[cur][(wn * 32 + j * 16 + l15) * 32 + ((quad ^ fsw) * 8)];
            bfl[j] = *(const bf16x8*)&BlL[cur][(wn * 32 + j * 16 + l15) * 32 + ((quad ^ fsw) * 8)];
        }
        if (kt + 1 < iters) {
            int k0 = (kt + 1) * 32;
            int nxt = 1 - cur;
            llds16(&AgL[nxt][wave * 512], ctxg + (size_t)(bm + wave * 16 + srow) * K + k0 + sg8);
            llds16(&AgL[nxt][(wave + 4) * 512], ctxg + (size_t)(bm + (wave + 4) * 16 + srow) * K + k0 + sg8);
            llds16(&AlL[nxt][wave * 512], ctxl + (size_t)(bm + wave * 16 + srow) * K + k0 + sg8);
            llds16(&AlL[nxt][(wave + 4) * 512], ctxl + (size_t)(bm + (wave + 4) * 16 + srow) * K + k0 + sg8);
            llds16(&BgL[nxt][wave * 512], Wg + (size_t)(bn + wave * 16 + srow) * K + k0 + sg8);
            llds16(&BlL[nxt][wave * 512], Wl + (size_t)(bn + wave * 16 + srow) * K + k0 + sg8);
        }
        #pragma unroll
        for (int i = 0; i < 4; ++i)
            #pragma unroll
            for (int j = 0; j < 2; ++j)
                accg[i][j] = MFMA16(bfg[j], afg[i], accg[i][j]);
        #pragma unroll
        for (int i = 0; i < 4; ++i)
            #pragma unroll
            for (int j = 0; j < 2; ++j)
                accl[i][j] = MFMA16(bfl[j], afl[i], accl[i][j]);
    }

    #pragma unroll
    for (int i = 0; i < 4; ++i) {
        int row = bm + wm * 64 + i * 16 + l15;
        int bb = (row >= Lh) ? 1 : 0;
        int n = row - bb * Lh;
        int ii = n / 48, jj = n % 48;
        float keepg = (fg[row] != 0.0f) ? 1.0f : 0.0f;
        float keepl = (keepg == 0.0f &&
                       bgw[bb * 36 + (ii >> 3) * 6 + (jj >> 3)] != 0.0f) ? 1.0f : 0.0f;
        #pragma unroll
        for (int j = 0; j < 2; ++j) {
            int col = bn + wn * 32 + j * 16 + quad * 4;
            float4 bg4 = *(const float4*)&biasg[col];
            float4 bl4 = *(const float4*)&biasl[col];
            float4 x4 = *(const float4*)&x[(size_t)row * N + col];
            float4 o;
            o.x = x4.x + keepg * (accg[i][j][0] + bg4.x) + keepl * (accl[i][j][0] + bl4.x);
            o.y = x4.y + keepg * (accg[i][j][1] + bg4.y) + keepl * (accl[i][j][1] + bl4.y);
            o.z = x4.z + keepg * (accg[i][j][2] + bg4.z) + keepl * (accl[i][j][2] + bl4.z);
            o.w = x4.w + keepg * (accg[i][j][3] + bg4.w) + keepl * (accl[i][j][3] + bl4.w);
            *(float4*)&x1[(size_t)row * N + col] = o;
        }
    }
}

// ---------------------------------------------------------------- fused attention
// R18 global body: 32x32x16 MFMA, in-register P (T12).
//   QK^T = MFMA32(K, Q): D col = lane&31 = q, row = (reg&3)+8*(reg>>2)+4*(lane>>5) = key.
//   P lane-local -> cvt_pk_bf16 pairs + permlane32_swap build the PV B-operand
//   (col=q, kk=key) with ZERO LDS round-trip. Mask via per-kt __ballot bitmask.
//   K [64][64] and V^T [64][64] staged via global_load_lds with chunk-XOR
//   swizzle (chunk' = chunk ^ (row&7)) -> conflict-free b128 frag reads.
//   LDS total 32 KB (K dbuf 16K + V dbuf 16K) -> ~5 blocks/CU.
__device__ __forceinline__ void attn_global_body(
    const ushort_t* __restrict__ QKV, const ushort_t* __restrict__ VT,
    const float* __restrict__ fg,
    float* __restrict__ Opart, float* __restrict__ Lpart,
    int tile, int h, int b, int half, ushort_t* SM)
{
    int tid = threadIdx.x;
    int lane = tid & 63;
    int wave = tid >> 6;
    int l31 = lane & 31;
    int hi = lane >> 5;               // kk-half selector
    int kb0 = half * 1152;            // key-token base for this half

    // Q frags: q = tile*128 + wave*32 + l31; aq[kkg] holds d = kkg*16 + hi*8 + j
    int tok_q = tile * 128 + wave * 32 + l31;
    bf16x8 aq[4];
    {
        const ushort_t* qbase = QKV + (size_t)(b * Lh + tok_q) * QS2 + h * 64 + hi * 8;
        #pragma unroll
        for (int kkg = 0; kkg < 4; ++kkg)
            aq[kkg] = *(const bf16x8*)(qbase + kkg * 16);
    }

    // staging: lane L covers row (wave*16 + c*8 + (L>>3)), phys chunk L&7
    // holding logical chunk (L&7)^(L>>3)  (row&7 == L>>3)
    int srow = lane >> 3;
    int schunk = (lane & 7) ^ srow;
    int krow0 = wave * 16 + srow;
    const ushort_t* ksrc  = QKV + (size_t)(b * Lh + kb0 + krow0) * QS2 + 768 + h * 64 + schunk * 8;
    const ushort_t* ksrc2 = ksrc + (size_t)8 * QS2;
    const ushort_t* vsrc  = VT + (size_t)(h * 64 + krow0) * 4608 + b * Lh + kb0 + schunk * 8;
    const ushort_t* vsrc2 = vsrc + (size_t)8 * 4608;

    ushort_t* KsB = SM;               // [2][64][64]
    ushort_t* VsB = SM + 8192;        // [2][64][64]
    int sdst = wave * 1024;           // ushort offset of wave's 16-row region

    float l_part = 0.f;
    f32x16 o_acc[2];
    #pragma unroll
    for (int dg = 0; dg < 2; ++dg)
        #pragma unroll
        for (int i = 0; i < 16; ++i) o_acc[dg][i] = 0.f;

    // prologue: stage tile 0 into buf 0
    llds16(KsB + sdst, ksrc);
    llds16(KsB + sdst + 512, ksrc2);
    llds16(VsB + sdst, vsrc);
    llds16(VsB + sdst + 512, vsrc2);
    float fgv = fg[b * Lh + kb0 + lane];

    for (int kt = 0; kt < 18; ++kt) {
        int cur = kt & 1, nxt = cur ^ 1;
        __syncthreads();
        unsigned long long m64 = __ballot(fgv != 0.0f);

        if (kt + 1 < 18) {
            const ushort_t* kp  = ksrc  + (size_t)(kt + 1) * 64 * QS2;
            const ushort_t* kp2 = ksrc2 + (size_t)(kt + 1) * 64 * QS2;
            llds16(KsB + nxt * 4096 + sdst, kp);
            llds16(KsB + nxt * 4096 + sdst + 512, kp2);
            llds16(VsB + nxt * 4096 + sdst, vsrc + (kt + 1) * 64);
            llds16(VsB + nxt * 4096 + sdst + 512, vsrc2 + (kt + 1) * 64);
            fgv = fg[b * Lh + kb0 + (kt + 1) * 64 + lane];
        }

        #pragma unroll
        for (int kg = 0; kg < 2; ++kg) {
            // QK^T for keys kg*32..kg*32+31
            f32x16 sA;
            #pragma unroll
            for (int i = 0; i < 16; ++i) sA[i] = 0.f;
            #pragma unroll
            for (int kkg = 0; kkg < 4; ++kkg) {
                bf16x8 bk = *(const bf16x8*)&KsB[cur * 4096 + (kg * 32 + l31) * 64 +
                                                 (((kkg * 2 + hi) ^ (l31 & 7)) * 8)];
                sA = MFMA32(bk, aq[kkg], sA);
            }
            // masked exp2: key = kg*32 + (reg&3) + 8*(reg>>2) + 4*hi
            float ev[16];
            #pragma unroll
            for (int r4 = 0; r4 < 4; ++r4) {
                uint_t bits = (uint_t)(m64 >> (kg * 32 + 8 * r4 + 4 * hi)) & 0xFu;
                #pragma unroll
                for (int s = 0; s < 4; ++s) {
                    float m = (bits & (1u << s)) ? 0.0f : -MSK2;
                    float e = EXP2F(sA[r4 * 4 + s] * SCL2 + m);
                    ev[r4 * 4 + s] = e;
                    l_part += e;
                }
            }
            // pack P into PV B-operand fragments (two 16-key tiles per kg)
            #pragma unroll
            for (int th = 0; th < 2; ++th) {
                int t16 = kg * 2 + th;
                uint_t w0 = cvtpk(ev[8 * th + 0], ev[8 * th + 1]);
                uint_t w1 = cvtpk(ev[8 * th + 2], ev[8 * th + 3]);
                uint_t w2 = cvtpk(ev[8 * th + 4], ev[8 * th + 5]);
                uint_t w3 = cvtpk(ev[8 * th + 6], ev[8 * th + 7]);
                plswap(w0, w2);
                plswap(w1, w3);
                union { uint_t u[4]; bf16x8 v; } pw;
                pw.u[0] = w0; pw.u[1] = w1; pw.u[2] = w2; pw.u[3] = w3;
                #pragma unroll
                for (int dg = 0; dg < 2; ++dg) {
                    bf16x8 bv = *(const bf16x8*)&VsB[cur * 4096 + (dg * 32 + l31) * 64 +
                                                     (((t16 * 2 + hi) ^ (l31 & 7)) * 8)];
                    o_acc[dg] = MFMA32(bv, pw.v, o_acc[dg]);
                }
            }
        }
    }

    // partial outputs: unnormalized o (f32) + l per (q,h)
    float lsum = l_part + __shfl_xor(l_part, 32, 64);
    float* op = Opart + ((size_t)half * 4608 + b * Lh + tok_q) * Ch + h * 64 + hi * 4;
    #pragma unroll
    for (int dg = 0; dg < 2; ++dg)
        #pragma unroll
        for (int r4 = 0; r4 < 4; ++r4) {
            *(float4*)(op + dg * 32 + r4 * 8) =
                make_float4(o_acc[dg][r4 * 4 + 0], o_acc[dg][r4 * 4 + 1],
                            o_acc[dg][r4 * 4 + 2], o_acc[dg][r4 * 4 + 3]);
        }
    if (hi == 0)
        Lpart[((size_t)half * 4608 + b * Lh + tok_q) * NHh + h] = lsum;
}

__device__ __forceinline__ void attn_local_body(
    const ushort_t* __restrict__ QKV, const ushort_t* __restrict__ VT,
    ushort_t* __restrict__ O, int tile, int h, int b,
    ushort_t (*Ks)[2][64][32], ushort_t (*Vs)[2][64][32], ushort_t (*Ps)[72])
{
    int tid = threadIdx.x;
    int lane = tid & 63;
    int wave = tid >> 6;
    int quad = lane >> 4, l15 = lane & 15;
    int wi = tile / 6, wj = tile % 6;

    bf16x8 aq[2];
    {
        int ql = wave * 16 + l15;
        int tok = (wi * 8 + (ql >> 3)) * 48 + wj * 8 + (ql & 7);
        const ushort_t* qbase = QKV + (size_t)(b * Lh + tok) * QS2 + 1536 + h * 64;
        #pragma unroll
        for (int step = 0; step < 2; ++step)
            aq[step] = *(const bf16x8*)(qbase + step * 32 + quad * 8);
    }

    // staging: K rows = window tokens; V rows = d, chunks = token-groups
    {
        int srow = lane >> 2;
        int sc = lane & 3;
        int krow = wave * 16 + srow;
        int kfs = (krow >> 1) & 3;
        int tokK = (wi * 8 + (krow >> 3)) * 48 + wj * 8 + (krow & 7);
        const ushort_t* ksrc = QKV + (size_t)(b * Lh + tokK) * QS2 + 2304 + h * 64 + (sc ^ kfs) * 8;
        int c0 = sc ^ kfs;
        const ushort_t* vbase = VT + (size_t)(768 + h * 64 + krow) * 4608 + b * Lh + wj * 8;
        llds16(&Ks[0][0][wave * 16][0], ksrc);
        llds16(&Ks[0][1][wave * 16][0], ksrc + 32);
        llds16(&Vs[0][0][wave * 16][0], vbase + (wi * 8 + c0) * 48);
        llds16(&Vs[0][1][wave * 16][0], vbase + (wi * 8 + 4 + c0) * 48);
    }
    __syncthreads();

    float l_part = 0.f;
    f32x4 o_acc[4];
    #pragma unroll
    for (int t4 = 0; t4 < 4; ++t4) o_acc[t4] = (f32x4){0.f, 0.f, 0.f, 0.f};

    int rfs = (l15 >> 1) & 3;
    f32x4 s4[4];
    #pragma unroll
    for (int j4 = 0; j4 < 4; ++j4) s4[j4] = (f32x4){0.f, 0.f, 0.f, 0.f};
    #pragma unroll
    for (int step = 0; step < 2; ++step) {
        bf16x8 bk[4];
        #pragma unroll
        for (int j4 = 0; j4 < 4; ++j4)
            bk[j4] = *(const bf16x8*)&Ks[0][step][j4 * 16 + l15][(quad ^ rfs) * 8];
        #pragma unroll
        for (int j4 = 0; j4 < 4; ++j4)
            s4[j4] = MFMA16(bk[j4], aq[step], s4[j4]);
    }
    int p0 = wave * 16;
    #pragma unroll
    for (int j4 = 0; j4 < 4; ++j4) {
        float e0 = EXP2F(s4[j4][0] * SCL2);
        float e1 = EXP2F(s4[j4][1] * SCL2);
        float e2 = EXP2F(s4[j4][2] * SCL2);
        float e3 = EXP2F(s4[j4][3] * SCL2);
        l_part += (e0 + e1) + (e2 + e3);
        uint_t a01 = __builtin_amdgcn_perm(__float_as_uint(e1), __float_as_uint(e0), 0x07060302u);
        uint_t a23 = __builtin_amdgcn_perm(__float_as_uint(e3), __float_as_uint(e2), 0x07060302u);
        *(uint2*)&Ps[p0 + l15][j4 * 16 + quad * 4] = make_uint2(a01, a23);
    }
    #pragma unroll
    for (int step = 0; step < 2; ++step) {
        bf16x8 bv[4];
        #pragma unroll
        for (int t4 = 0; t4 < 4; ++t4)
            bv[t4] = *(const bf16x8*)&Vs[0][step][t4 * 16 + l15][(quad ^ rfs) * 8];
        bf16x8 a = *(const bf16x8*)&Ps[p0 + l15][step * 32 + quad * 8];
        #pragma unroll
        for (int t4 = 0; t4 < 4; ++t4)
            o_acc[t4] = MFMA16(bv[t4], a, o_acc[t4]);   // swapped: lane=q
    }

    {
        float v = l_part;
        v += __shfl_xor(v, 16, 64);
        v += __shfl_xor(v, 32, 64);
        float inv = 1.0f / v;
        int ql = wave * 16 + l15;
        int tok = (wi * 8 + (ql >> 3)) * 48 + wj * 8 + (ql & 7);
        ushort_t* ob = O + (size_t)(b * Lh + tok) * Ch + h * 64;
        #pragma unroll
        for (int t4 = 0; t4 < 4; ++t4) {
            *(uint2*)&ob[t4 * 16 + quad * 4] =
                make_uint2(pack2bf(o_acc[t4][0] * inv, o_acc[t4][1] * inv),
                           pack2bf(o_acc[t4][2] * inv, o_acc[t4][3] * inv));
        }
    }
}

__global__ __launch_bounds__(256)
void attn_fused_kernel(const ushort_t* __restrict__ QKV, const ushort_t* __restrict__ VT,
                       const float* __restrict__ fg,
                       float* __restrict__ Opart, float* __restrict__ Lpart,
                       ushort_t* __restrict__ ctxl)
{
    // 32 KB shared pool: global uses K[2][64][64] + V[2][64][64];
    // local carves K(8K) + V(8K) + Ps(9.2K) from the same pool.
    __shared__ __align__(16) ushort_t SM[16384];

    int bid = blockIdx.x;
    if (bid < 864) {
        // bijective XCD swizzle: 108 consecutive logical blocks per XCD
        int gid = (bid & 7) * 108 + (bid >> 3);
        int half = gid / 432;
        int rem = gid % 432;
        int tile = rem % 18;
        int h = (rem / 18) % NHh;
        int b = rem / 216;
        attn_global_body(QKV, VT, fg, Opart, Lpart, tile, h, b, half, SM);
    } else {
        int rr = bid - 864;
        int lid = (rr & 7) * 108 + (rr >> 3);
        int tile = lid % 36;
        int h = (lid / 36) % NHh;
        int b = lid / 432;
        attn_local_body(QKV, VT, ctxl, tile, h, b,
                        (ushort_t(*)[2][64][32])SM,
                        (ushort_t(*)[2][64][32])(SM + 4096),
                        (ushort_t(*)[72])(SM + 8192));
    }
}

// ---------------------------------------------------------------- split-KV merge
// ctxg[r][d] = (Oa[r][d] + Ob[r][d]) / (La[r][h] + Lb[r][h]), bf16 out
__global__ __launch_bounds__(192)
void attn_merge_kernel(const float* __restrict__ Op, const float* __restrict__ Lp,
                       ushort_t* __restrict__ ctxg)
{
    int r = blockIdx.x;
    int tid = threadIdx.x;
    int d = tid * 4;
    int h = d >> 6;
    float la = Lp[(size_t)r * NHh + h];
    float lb = Lp[((size_t)4608 + r) * NHh + h];
    float inv = 1.0f / (la + lb);
    const float* pa = Op + (size_t)r * Ch + d;
    const float* pb = Op + (size_t)4608 * Ch + (size_t)r * Ch + d;
    float4 a = *(const float4*)pa;
    float4 b4 = *(const float4*)pb;
    *(uint2*)&ctxg[(size_t)r * Ch + d] =
        make_uint2(pack2bf((a.x + b4.x) * inv, (a.y + b4.y) * inv),
                   pack2bf((a.z + b4.z) * inv, (a.w + b4.w) * inv));
}

// ---------------------------------------------------------------- launch
extern "C" void kernel_launch(void* const* d_in, const int* in_sizes, int n_in,
                              void* d_out, int out_size, void* d_ws, size_t ws_size,
                              hipStream_t stream)
{
    const float* x       = (const float*)d_in[0];
    const float* mask    = (const float*)d_in[1];
    const float* w_qkv_g = (const float*)d_in[2];
    const float* b_qkv_g = (const float*)d_in[3];
    const float* w_o_g   = (const float*)d_in[4];
    const float* b_o_g   = (const float*)d_in[5];
    const float* w_qkv_l = (const float*)d_in[6];
    const float* b_qkv_l = (const float*)d_in[7];
    const float* w_o_l   = (const float*)d_in[8];
    const float* b_o_l   = (const float*)d_in[9];
    const float* ln1_w   = (const float*)d_in[10];
    const float* ln1_b   = (const float*)d_in[11];
    const float* ln2_w   = (const float*)d_in[12];
    const float* ln2_b   = (const float*)d_in[13];
    const float* w_fc1   = (const float*)d_in[14];
    const float* b_fc1   = (const float*)d_in[15];
    const float* w_fc2   = (const float*)d_in[16];
    const float* b_fc2   = (const float*)d_in[17];
    float* out = (float*)d_out;

    const size_t U = (size_t)Bh * Lh * Ch;           // 3,538,944
    char* p = (char*)d_ws;
    ushort_t* qkvb = (ushort_t*)p;        p += (size_t)4608 * 3072 * 2;  // [4608][qg|kg|ql|kl]
    ushort_t* vtb  = (ushort_t*)p;        p += (size_t)1536 * 4608 * 2;  // V^T [col'][token]
    ushort_t* midb = qkvb;                                               // [4608][3072] aliases
    ushort_t* ctxg = (ushort_t*)p;        p += U * 2;
    ushort_t* ctxl = (ushort_t*)p;        p += U * 2;
    ushort_t* xnb  = (ushort_t*)p;        p += U * 2;
    float*    Opart = (float*)p;          p += (size_t)2 * U * 4;        // f32 partials (2 halves)
    float*    Lpart = (float*)p;          p += (size_t)2 * 4608 * NHh * 4;
    float*    x1   = Opart;               // alias: x1 live only after merge consumed Opart
    ushort_t* wtq  = (ushort_t*)p;        p += (size_t)4608 * 768 * 2;   // qkv g|l concat
    ushort_t* wt_o_g = (ushort_t*)p;      p += (size_t)768 * 768 * 2;
    ushort_t* wt_o_l = (ushort_t*)p;      p += (size_t)768 * 768 * 2;
    ushort_t* wt_fc1 = (ushort_t*)p;      p += (size_t)3072 * 768 * 2;
    ushort_t* wt_fc2 = (ushort_t*)p;      p += (size_t)768 * 3072 * 2;
    float*    biasq  = (float*)p;         p += 4608 * 4;
    float*    fg     = (float*)p;         p += Bh * Lh * 4;
    float*    bgw    = (float*)p;

    const int Mrows = Bh * Lh;                   // 4608
    dim3 blk(256);

    // weights + biases (blocks 2304/2305 copy biasq)
    transpose_all_kernel<<<2306, blk, 0, stream>>>(
        w_qkv_g, w_qkv_l, w_o_g, w_o_l, w_fc1, w_fc2, b_qkv_g, b_qkv_l,
        wtq, wt_o_g, wt_o_l, wt_fc1, wt_fc2, biasq);

    // ln1 + mask fused (blocks 4608..4679 do the mask windows)
    ln_mask_kernel<<<4680, blk, 0, stream>>>(x, ln1_w, ln1_b, xnb, mask, fg, bgw);

    // QKV GEMM: Q|K tiles (swapped MFMA) and V tiles (unswapped, V^T out)
    gemm_bf16_t<128, 0><<<dim3(24, Mrows / 128), blk, 0, stream>>>(
        xnb, wtq, biasq, nullptr, qkvb, nullptr, Mrows, 4608, Ch, 4);
    gemm_bf16_t<128, 1><<<dim3(12, Mrows / 128), blk, 0, stream>>>(
        xnb, wtq, biasq, nullptr, nullptr, vtb, Mrows, 4608, Ch, 4);

    // fused attention: 864 global split-KV blocks (32x32 path) + 864 local blocks
    attn_fused_kernel<<<1728, blk, 0, stream>>>(qkvb, vtb, fg, Opart, Lpart, ctxl);
    attn_merge_kernel<<<Mrows, dim3(192), 0, stream>>>(Opart, Lpart, ctxg);

    // dual masked o-projection -> x1 (one fused dispatch, single K-loop)
    oproj_dual_kernel<<<dim3(Ch / 64, Mrows / 128), blk, 0, stream>>>(
        ctxg, ctxl, wt_o_g, wt_o_l, b_o_g, b_o_l, x, x1, fg, bgw);

    layernorm_bf16_kernel<<<Mrows, blk, 0, stream>>>(x1, ln2_w, ln2_b, xnb);

    // MLP
    gemm_bf16_t<128, 0><<<dim3(3072 / 128, Mrows / 128), blk, 0, stream>>>(
        xnb, wt_fc1, b_fc1, nullptr, midb, nullptr, Mrows, 3072, Ch, 1 | 2);
    gemm_bf16_t<64, 0><<<dim3(Ch / 64, Mrows / 128), blk, 0, stream>>>(
        midb, wt_fc2, b_fc2, x1, out, nullptr, Mrows, Ch, 3072, 0);
}

// Round 9
// 395.863 us; speedup vs baseline: 1.0329x; 1.0329x over previous
//
#include <hip/hip_runtime.h>
#include <math.h>

#define Lh 2304
#define Ch 768
#define NHh 12
#define Bh 2
#define QS2 3072  // row stride of packed qkv activation buffer [qg|kg|ql|kl]

typedef unsigned short ushort_t;
typedef unsigned int uint_t;
typedef __attribute__((ext_vector_type(8))) short bf16x8;
typedef __attribute__((ext_vector_type(4))) float f32x4;
typedef __attribute__((ext_vector_type(16))) float f32x16;
#define MFMA16(a, b, c) __builtin_amdgcn_mfma_f32_16x16x32_bf16(a, b, c, 0, 0, 0)
#define MFMA32(a, b, c) __builtin_amdgcn_mfma_f32_32x32x16_bf16(a, b, c, 0, 0, 0)

// softmax in exp2 domain: exp(s*0.125 + m) == exp2(s*SCL2 + m*log2e)  (R1-validated)
#define SCL2 0.18033688f        // 0.125 * log2(e)
#define MSK2 1.4426950e9f       // 1e9  * log2(e)
#if __has_builtin(__builtin_amdgcn_exp2f)
#define EXP2F(x) __builtin_amdgcn_exp2f(x)
#else
#define EXP2F(x) exp2f(x)
#endif

__device__ __forceinline__ ushort_t f2bf(float f) {
    union { float f; uint_t u; } v; v.f = f;
    uint_t u = v.u + 0x7fffu + ((v.u >> 16) & 1u);   // RNE
    return (ushort_t)(u >> 16);
}
// pack 2 fp32 -> 2 bf16 (RNE) into one u32
__device__ __forceinline__ uint_t pack2bf(float a, float b) {
    return (uint_t)f2bf(a) | ((uint_t)f2bf(b) << 16);
}
// packed f32->bf16 pair (T12; no builtin on gfx950)
__device__ __forceinline__ uint_t cvtpk(float lo, float hi) {
    uint_t r;
    asm("v_cvt_pk_bf16_f32 %0, %1, %2" : "=v"(r) : "v"(lo), "v"(hi));
    return r;
}
// exchange a's upper 32 lanes with b's lower 32 lanes (both outputs usable)
__device__ __forceinline__ void plswap(uint_t& a, uint_t& b) {
    asm volatile("v_permlane32_swap_b32 %0, %1" : "+v"(a), "+v"(b));
}

// async global->LDS, 16B/lane, dest = wave-uniform base + lane*16
__device__ __forceinline__ void llds16(ushort_t* dst, const ushort_t* src) {
    __builtin_amdgcn_global_load_lds(
        (__attribute__((address_space(1))) void*)(const_cast<ushort_t*>(src)),
        (__attribute__((address_space(3))) void*)dst, 16, 0, 0);
}

// ---------------------------------------------------------------- layernorm (fp32 in, bf16 out)
__device__ __forceinline__ void ln_body(const float* __restrict__ x, const float* __restrict__ w,
                                        const float* __restrict__ b, ushort_t* __restrict__ y,
                                        int row, float* red)
{
    int tid = threadIdx.x;
    const float* xr = x + (size_t)row * Ch;
    float v0 = xr[tid], v1 = xr[tid + 256], v2 = xr[tid + 512];
    red[tid] = v0 + v1 + v2;
    __syncthreads();
    for (int st = 128; st > 0; st >>= 1) {
        if (tid < st) red[tid] += red[tid + st];
        __syncthreads();
    }
    float mean = red[0] * (1.0f / 768.0f);
    __syncthreads();
    float d0 = v0 - mean, d1 = v1 - mean, d2 = v2 - mean;
    red[tid] = d0 * d0 + d1 * d1 + d2 * d2;
    __syncthreads();
    for (int st = 128; st > 0; st >>= 1) {
        if (tid < st) red[tid] += red[tid + st];
        __syncthreads();
    }
    float rstd = rsqrtf(red[0] * (1.0f / 768.0f) + 1e-6f);
    ushort_t* yr = y + (size_t)row * Ch;
    yr[tid]       = f2bf(d0 * rstd * w[tid]       + b[tid]);
    yr[tid + 256] = f2bf(d1 * rstd * w[tid + 256] + b[tid + 256]);
    yr[tid + 512] = f2bf(d2 * rstd * w[tid + 512] + b[tid + 512]);
}

__global__ __launch_bounds__(256)
void layernorm_bf16_kernel(const float* __restrict__ x, const float* __restrict__ w,
                           const float* __restrict__ b, ushort_t* __restrict__ y)
{
    __shared__ float red[256];
    ln_body(x, w, b, y, blockIdx.x, red);
}

// ln1 + mask fused into one dispatch (block-uniform branch)
__global__ __launch_bounds__(256)
void ln_mask_kernel(const float* __restrict__ x, const float* __restrict__ w,
                    const float* __restrict__ b, ushort_t* __restrict__ y,
                    const float* __restrict__ mask, float* __restrict__ fg,
                    float* __restrict__ bgw)
{
    __shared__ float red[256];
    int bid = blockIdx.x;
    if (bid < 4608) {
        ln_body(x, w, b, y, bid, red);
        return;
    }
    int win = bid - 4608;            // 0..71
    int tid = threadIdx.x;
    if (tid >= 64) return;
    int bb = win / 36, ww = win % 36;
    int wi = ww / 6, wj = ww % 6;
    int i = wi * 8 + (tid >> 3), j = wj * 8 + (tid & 7);
    const float* mb = mask + (size_t)bb * 192 * 192 + (size_t)(i * 4) * 192 + j * 4;
    float s = 0.0f;
    #pragma unroll
    for (int di = 0; di < 4; ++di) {
        float4 v = *(const float4*)(mb + (size_t)di * 192);
        s += v.x + v.y + v.z + v.w;
    }
    float f = (s * (1.0f / 16.0f) > 0.4f) ? 1.0f : 0.0f;
    fg[bb * Lh + i * 48 + j] = f;
    unsigned long long bg = __ballot(f == 0.0f);
    if (tid == 0) bgw[win] = bg ? 1.0f : 0.0f;
}

// ---------------------------------------------------------------- batched weight cast+transpose
// blocks 2304/2305 copy the qkv biases (replaces 2 hipMemcpyAsync launches)
__global__ __launch_bounds__(256)
void transpose_all_kernel(const float* __restrict__ w_qkv_g, const float* __restrict__ w_qkv_l,
                          const float* __restrict__ w_o_g, const float* __restrict__ w_o_l,
                          const float* __restrict__ w_fc1, const float* __restrict__ w_fc2,
                          const float* __restrict__ b_qkv_g, const float* __restrict__ b_qkv_l,
                          ushort_t* __restrict__ wtq, ushort_t* __restrict__ wt_o_g,
                          ushort_t* __restrict__ wt_o_l, ushort_t* __restrict__ wt_fc1,
                          ushort_t* __restrict__ wt_fc2, float* __restrict__ biasq)
{
    int blk = blockIdx.x;
    int tid = threadIdx.x;
    if (blk >= 2304) {
        int which = blk - 2304;
        const float* src = which ? b_qkv_l : b_qkv_g;
        float* dst = biasq + which * 2304;
        for (int i = tid; i < 2304; i += 256) dst[i] = src[i];
        return;
    }
    const float* W; ushort_t* D; int K, N, nx, bx;
    const size_t CC = (size_t)Ch * Ch;
    if (blk < 432)       { int t = blk / 144; bx = blk % 144;
                           W = w_qkv_g + t * CC; D = wtq + t * CC; K = 768; N = 768; nx = 12; }
    else if (blk < 864)  { int r = blk - 432; int t = r / 144; bx = r % 144;
                           W = w_qkv_l + t * CC; D = wtq + (size_t)2304 * 768 + t * CC;
                           K = 768; N = 768; nx = 12; }
    else if (blk < 1008) { bx = blk - 864;  W = w_o_g; D = wt_o_g; K = 768; N = 768; nx = 12; }
    else if (blk < 1152) { bx = blk - 1008; W = w_o_l; D = wt_o_l; K = 768; N = 768; nx = 12; }
    else if (blk < 1728) { bx = blk - 1152; W = w_fc1; D = wt_fc1; K = 768; N = 3072; nx = 48; }
    else                 { bx = blk - 1728; W = w_fc2; D = wt_fc2; K = 3072; N = 768; nx = 12; }
    int n0 = (bx % nx) * 64;
    int k0 = (bx / nx) * 64;
    __shared__ float T[64][65];
    #pragma unroll
    for (int i = 0; i < 16; ++i) {
        int lin = i * 256 + tid;
        int r = lin >> 6, c = lin & 63;
        T[r][c] = W[(size_t)(k0 + r) * N + n0 + c];
    }
    __syncthreads();
    // vectorized: each unit = (n-row r, 4 consecutive k) -> one b64 store
    #pragma unroll
    for (int i = 0; i < 4; ++i) {
        int lin = i * 256 + tid;          // 0..1023
        int r = lin >> 4, c0 = (lin & 15) * 4;
        uint_t lo = pack2bf(T[c0][r], T[c0 + 1][r]);
        uint_t hi = pack2bf(T[c0 + 2][r], T[c0 + 3][r]);
        *(uint2*)&D[(size_t)(n0 + r) * K + k0 + c0] = make_uint2(lo, hi);
    }
}

// ---------------------------------------------------------------- bf16 MFMA GEMM body
// flags: 1=gelu, 2=bf16 out, 4=qkv split-store (packed [qg|kg|ql|kl], stride 3072)
// VMODE=1 = V column-tiles with unswapped MFMA -> acc lane = output col (d),
// quad*4+r = 4 consecutive tokens -> coalesced uint2 V^T stores. VMODE is a
// compile-time param; the QKV kernel branches between bodies at KERNEL TOP
// (R5 lesson: a runtime branch inside the K-loop breaks pipelining).
template<int BNt, int VMODE>
__device__ __forceinline__ void gemm_body(
    const ushort_t* __restrict__ A, const ushort_t* __restrict__ Bt,
    const float* __restrict__ bias, const float* __restrict__ residual,
    void* __restrict__ C, ushort_t* __restrict__ vt,
    int M, int N, int K, int flags, int bm, int bn, ushort_t* pool)
{
    ushort_t (*AsL)[128 * 32] = (ushort_t(*)[128 * 32])pool;
    ushort_t (*BsL)[BNt * 32] = (ushort_t(*)[BNt * 32])(pool + 2 * 128 * 32);
    int tid = threadIdx.x;
    int lane = tid & 63;
    int wave = tid >> 6;
    int wm = wave >> 1, wn = wave & 1;
    int quad = lane >> 4, l15 = lane & 15;
    constexpr int NJ = BNt / 32;

    int srow = lane >> 2;
    int sg8 = ((lane & 3) ^ ((lane >> 3) & 3)) * 8;
    int fsw = (l15 >> 1) & 3;

    f32x4 acc[4][NJ];
    #pragma unroll
    for (int i = 0; i < 4; ++i)
        #pragma unroll
        for (int j = 0; j < NJ; ++j)
            acc[i][j] = (f32x4){0.f, 0.f, 0.f, 0.f};

    int iters = K / 32;
    llds16(&AsL[0][wave * 512], A + (size_t)(bm + wave * 16 + srow) * K + sg8);
    llds16(&AsL[0][(wave + 4) * 512], A + (size_t)(bm + (wave + 4) * 16 + srow) * K + sg8);
    llds16(&BsL[0][wave * 512], Bt + (size_t)(bn + wave * 16 + srow) * K + sg8);
    if (BNt == 128)
        llds16(&BsL[0][(wave + 4) * 512], Bt + (size_t)(bn + (wave + 4) * 16 + srow) * K + sg8);

    for (int kt = 0; kt < iters; ++kt) {
        int cur = kt & 1;
        __syncthreads();

        bf16x8 af[4], bfr[NJ];
        #pragma unroll
        for (int i = 0; i < 4; ++i)
            af[i] = *(const bf16x8*)&AsL[cur][(wm * 64 + i * 16 + l15) * 32 + ((quad ^ fsw) * 8)];
        #pragma unroll
        for (int j = 0; j < NJ; ++j)
            bfr[j] = *(const bf16x8*)&BsL[cur][(wn * (BNt / 2) + j * 16 + l15) * 32 + ((quad ^ fsw) * 8)];

        if (kt + 1 < iters) {
            int k0 = (kt + 1) * 32;
            int nxt = 1 - cur;
            llds16(&AsL[nxt][wave * 512], A + (size_t)(bm + wave * 16 + srow) * K + k0 + sg8);
            llds16(&AsL[nxt][(wave + 4) * 512], A + (size_t)(bm + (wave + 4) * 16 + srow) * K + k0 + sg8);
            llds16(&BsL[nxt][wave * 512], Bt + (size_t)(bn + wave * 16 + srow) * K + k0 + sg8);
            if (BNt == 128)
                llds16(&BsL[nxt][(wave + 4) * 512], Bt + (size_t)(bn + (wave + 4) * 16 + srow) * K + k0 + sg8);
        }

        if constexpr (VMODE == 0) {
            // swapped operands: lane = A row (output row), quad*4+r = B row (output col)
            #pragma unroll
            for (int i = 0; i < 4; ++i)
                #pragma unroll
                for (int j = 0; j < NJ; ++j)
                    acc[i][j] = MFMA16(bfr[j], af[i], acc[i][j]);
        } else {
            // unswapped: lane = B row (output col/d), quad*4+r = A row (token)
            #pragma unroll
            for (int i = 0; i < 4; ++i)
                #pragma unroll
                for (int j = 0; j < NJ; ++j)
                    acc[i][j] = MFMA16(af[i], bfr[j], acc[i][j]);
        }
    }

    if constexpr (VMODE == 1) {
        #pragma unroll
        for (int j = 0; j < NJ; ++j) {
            int col = bn + wn * (BNt / 2) + j * 16 + l15;
            int colp = col - ((col >= 3840) ? 3072 : 1536);
            float bc = bias[col];
            #pragma unroll
            for (int i = 0; i < 4; ++i) {
                int row0 = bm + wm * 64 + i * 16 + quad * 4;
                *(uint2*)&vt[(size_t)colp * 4608 + row0] =
                    make_uint2(pack2bf(acc[i][j][0] + bc, acc[i][j][1] + bc),
                               pack2bf(acc[i][j][2] + bc, acc[i][j][3] + bc));
            }
        }
        return;
    }

    #pragma unroll
    for (int i = 0; i < 4; ++i) {
        int row = bm + wm * 64 + i * 16 + l15;
        #pragma unroll
        for (int j = 0; j < NJ; ++j) {
            int col = bn + wn * (BNt / 2) + j * 16 + quad * 4;
            float4 bia = *(const float4*)&bias[col];
            float o0 = acc[i][j][0] + bia.x;
            float o1 = acc[i][j][1] + bia.y;
            float o2 = acc[i][j][2] + bia.z;
            float o3 = acc[i][j][3] + bia.w;
            if (flags & 1) {
                o0 = o0 * 0.5f * (1.0f + erff(o0 * 0.70710678f));
                o1 = o1 * 0.5f * (1.0f + erff(o1 * 0.70710678f));
                o2 = o2 * 0.5f * (1.0f + erff(o2 * 0.70710678f));
                o3 = o3 * 0.5f * (1.0f + erff(o3 * 0.70710678f));
            }
            if (residual) {
                float4 rs = *(const float4*)&residual[(size_t)row * N + col];
                o0 += rs.x; o1 += rs.y; o2 += rs.z; o3 += rs.w;
            }
            if (flags & 4) {
                int cq = col - ((col >= 2304) ? 768 : 0);
                *(uint2*)&((ushort_t*)C)[(size_t)row * QS2 + cq] =
                    make_uint2(pack2bf(o0, o1), pack2bf(o2, o3));
            } else if (flags & 2) {
                *(uint2*)&((ushort_t*)C)[(size_t)row * N + col] =
                    make_uint2(pack2bf(o0, o1), pack2bf(o2, o3));
            } else {
                *(float4*)&((float*)C)[(size_t)row * N + col] =
                    make_float4(o0, o1, o2, o3);
            }
        }
    }
}

template<int BNt>
__global__ __launch_bounds__(256)
void gemm_bf16_t(const ushort_t* __restrict__ A, const ushort_t* __restrict__ Bt,
                 const float* __restrict__ bias, const float* __restrict__ residual,
                 void* __restrict__ C, int M, int N, int K, int flags)
{
    __shared__ ushort_t pool[2 * 128 * 32 + 2 * BNt * 32];
    gemm_body<BNt, 0>(A, Bt, bias, residual, C, nullptr, M, N, K, flags,
                      blockIdx.y * 128, blockIdx.x * BNt, pool);
}

// R19: single QKV dispatch; bx<24 = Q|K tiles (VMODE 0), bx>=24 = V tiles
// (VMODE 1, V^T out). Top-level branch (two disjoint inlined bodies) — the
// V blocks fill the QK tail and one launch disappears.
__global__ __launch_bounds__(256)
void qkv_gemm_kernel(const ushort_t* __restrict__ A, const ushort_t* __restrict__ Bt,
                     const float* __restrict__ biasq, ushort_t* __restrict__ qkv,
                     ushort_t* __restrict__ vt)
{
    __shared__ ushort_t pool[4 * 128 * 32];
    int bx = blockIdx.x;
    int bm = blockIdx.y * 128;
    if (bx < 24) {
        int bn = (bx < 12) ? bx * 128 : 2304 + (bx - 12) * 128;
        gemm_body<128, 0>(A, Bt, biasq, nullptr, qkv, nullptr, 4608, 4608, Ch, 4, bm, bn, pool);
    } else {
        int bxx = bx - 24;
        int bn = (bxx < 6) ? 1536 + bxx * 128 : 3840 + (bxx - 6) * 128;
        gemm_body<128, 1>(A, Bt, biasq, nullptr, nullptr, vt, 4608, 4608, Ch, 4, bm, bn, pool);
    }
}

// ---------------------------------------------------------------- dual o-projection
// single fused 24-kt loop staging all four tiles (Ag, Al, Bg, Bl) ->
// 16 MFMAs per barrier. LDS 48 KB.
__global__ __launch_bounds__(256)
void oproj_dual_kernel(const ushort_t* __restrict__ ctxg, const ushort_t* __restrict__ ctxl,
                       const ushort_t* __restrict__ Wg, const ushort_t* __restrict__ Wl,
                       const float* __restrict__ biasg, const float* __restrict__ biasl,
                       const float* __restrict__ x, float* __restrict__ x1,
                       const float* __restrict__ fg, const float* __restrict__ bgw)
{
    __shared__ ushort_t AgL[2][128 * 32];
    __shared__ ushort_t AlL[2][128 * 32];
    __shared__ ushort_t BgL[2][64 * 32];
    __shared__ ushort_t BlL[2][64 * 32];
    int bm = blockIdx.y * 128;
    int bn = blockIdx.x * 64;
    int tid = threadIdx.x;
    int lane = tid & 63;
    int wave = tid >> 6;
    int wm = wave >> 1, wn = wave & 1;
    int quad = lane >> 4, l15 = lane & 15;

    int srow = lane >> 2;
    int sg8 = ((lane & 3) ^ ((lane >> 3) & 3)) * 8;
    int fsw = (l15 >> 1) & 3;
    const int K = Ch, N = Ch, iters = Ch / 32;

    f32x4 accg[4][2], accl[4][2];
    #pragma unroll
    for (int i = 0; i < 4; ++i)
        #pragma unroll
        for (int j = 0; j < 2; ++j) {
            accg[i][j] = (f32x4){0.f, 0.f, 0.f, 0.f};
            accl[i][j] = (f32x4){0.f, 0.f, 0.f, 0.f};
        }

    llds16(&AgL[0][wave * 512], ctxg + (size_t)(bm + wave * 16 + srow) * K + sg8);
    llds16(&AgL[0][(wave + 4) * 512], ctxg + (size_t)(bm + (wave + 4) * 16 + srow) * K + sg8);
    llds16(&AlL[0][wave * 512], ctxl + (size_t)(bm + wave * 16 + srow) * K + sg8);
    llds16(&AlL[0][(wave + 4) * 512], ctxl + (size_t)(bm + (wave + 4) * 16 + srow) * K + sg8);
    llds16(&BgL[0][wave * 512], Wg + (size_t)(bn + wave * 16 + srow) * K + sg8);
    llds16(&BlL[0][wave * 512], Wl + (size_t)(bn + wave * 16 + srow) * K + sg8);

    for (int kt = 0; kt < iters; ++kt) {
        int cur = kt & 1;
        __syncthreads();
        bf16x8 afg[4], afl[4], bfg[2], bfl[2];
        #pragma unroll
        for (int i = 0; i < 4; ++i) {
            afg[i] = *(const bf16x8*)&AgL[cur][(wm * 64 + i * 16 + l15) * 32 + ((quad ^ fsw) * 8)];
            afl[i] = *(const bf16x8*)&AlL[cur][(wm * 64 + i * 16 + l15) * 32 + ((quad ^ fsw) * 8)];
        }
        #pragma unroll
        for (int j = 0; j < 2; ++j) {
            bfg[j] = *(const bf16x8*)&BgL[cur][(wn * 32 + j * 16 + l15) * 32 + ((quad ^ fsw) * 8)];
            bfl[j] = *(const bf16x8*)&BlL[cur][(wn * 32 + j * 16 + l15) * 32 + ((quad ^ fsw) * 8)];
        }
        if (kt + 1 < iters) {
            int k0 = (kt + 1) * 32;
            int nxt = 1 - cur;
            llds16(&AgL[nxt][wave * 512], ctxg + (size_t)(bm + wave * 16 + srow) * K + k0 + sg8);
            llds16(&AgL[nxt][(wave + 4) * 512], ctxg + (size_t)(bm + (wave + 4) * 16 + srow) * K + k0 + sg8);
            llds16(&AlL[nxt][wave * 512], ctxl + (size_t)(bm + wave * 16 + srow) * K + k0 + sg8);
            llds16(&AlL[nxt][(wave + 4) * 512], ctxl + (size_t)(bm + (wave + 4) * 16 + srow) * K + k0 + sg8);
            llds16(&BgL[nxt][wave * 512], Wg + (size_t)(bn + wave * 16 + srow) * K + k0 + sg8);
            llds16(&BlL[nxt][wave * 512], Wl + (size_t)(bn + wave * 16 + srow) * K + k0 + sg8);
        }
        #pragma unroll
        for (int i = 0; i < 4; ++i)
            #pragma unroll
            for (int j = 0; j < 2; ++j)
                accg[i][j] = MFMA16(bfg[j], afg[i], accg[i][j]);
        #pragma unroll
        for (int i = 0; i < 4; ++i)
            #pragma unroll
            for (int j = 0; j < 2; ++j)
                accl[i][j] = MFMA16(bfl[j], afl[i], accl[i][j]);
    }

    #pragma unroll
    for (int i = 0; i < 4; ++i) {
        int row = bm + wm * 64 + i * 16 + l15;
        int bb = (row >= Lh) ? 1 : 0;
        int n = row - bb * Lh;
        int ii = n / 48, jj = n % 48;
        float keepg = (fg[row] != 0.0f) ? 1.0f : 0.0f;
        float keepl = (keepg == 0.0f &&
                       bgw[bb * 36 + (ii >> 3) * 6 + (jj >> 3)] != 0.0f) ? 1.0f : 0.0f;
        #pragma unroll
        for (int j = 0; j < 2; ++j) {
            int col = bn + wn * 32 + j * 16 + quad * 4;
            float4 bg4 = *(const float4*)&biasg[col];
            float4 bl4 = *(const float4*)&biasl[col];
            float4 x4 = *(const float4*)&x[(size_t)row * N + col];
            float4 o;
            o.x = x4.x + keepg * (accg[i][j][0] + bg4.x) + keepl * (accl[i][j][0] + bl4.x);
            o.y = x4.y + keepg * (accg[i][j][1] + bg4.y) + keepl * (accl[i][j][1] + bl4.y);
            o.z = x4.z + keepg * (accg[i][j][2] + bg4.z) + keepl * (accl[i][j][2] + bl4.z);
            o.w = x4.w + keepg * (accg[i][j][3] + bg4.w) + keepl * (accl[i][j][3] + bl4.w);
            *(float4*)&x1[(size_t)row * N + col] = o;
        }
    }
}

// ---------------------------------------------------------------- fused attention
// R18/R19 global body: 32x32x16 MFMA, in-register P (T12).
//   QK^T = MFMA32(K, Q): D col = lane&31 = q, row = (reg&3)+8*(reg>>2)+4*(lane>>5) = key.
//   P lane-local -> cvt_pk_bf16 pairs + permlane32_swap build the PV B-operand
//   with ZERO LDS round-trip. R19: mask addend via fgs[2][64] LDS float4
//   broadcast (R8's ballot-bit extraction cost ~60 VALU/kt/wave: VALUBusy 54%).
//   K [64][64] and V^T [64][64] staged via global_load_lds with chunk-XOR
//   swizzle (chunk' = chunk ^ (row&7)) -> conflict-free b128 frag reads.
__device__ __forceinline__ void attn_global_body(
    const ushort_t* __restrict__ QKV, const ushort_t* __restrict__ VT,
    const float* __restrict__ fg,
    float* __restrict__ Opart, float* __restrict__ Lpart,
    int tile, int h, int b, int half, ushort_t* SM, float (*fgs)[64])
{
    int tid = threadIdx.x;
    int lane = tid & 63;
    int wave = tid >> 6;
    int l31 = lane & 31;
    int hi = lane >> 5;               // kk-half selector
    int kb0 = half * 1152;            // key-token base for this half

    // Q frags: q = tile*128 + wave*32 + l31; aq[kkg] holds d = kkg*16 + hi*8 + j
    int tok_q = tile * 128 + wave * 32 + l31;
    bf16x8 aq[4];
    {
        const ushort_t* qbase = QKV + (size_t)(b * Lh + tok_q) * QS2 + h * 64 + hi * 8;
        #pragma unroll
        for (int kkg = 0; kkg < 4; ++kkg)
            aq[kkg] = *(const bf16x8*)(qbase + kkg * 16);
    }

    // staging: lane L covers row (wave*16 + c*8 + (L>>3)), phys chunk L&7
    // holding logical chunk (L&7)^(L>>3)  (row&7 == L>>3)
    int srow = lane >> 3;
    int schunk = (lane & 7) ^ srow;
    int krow0 = wave * 16 + srow;
    const ushort_t* ksrc  = QKV + (size_t)(b * Lh + kb0 + krow0) * QS2 + 768 + h * 64 + schunk * 8;
    const ushort_t* ksrc2 = ksrc + (size_t)8 * QS2;
    const ushort_t* vsrc  = VT + (size_t)(h * 64 + krow0) * 4608 + b * Lh + kb0 + schunk * 8;
    const ushort_t* vsrc2 = vsrc + (size_t)8 * 4608;

    ushort_t* KsB = SM;               // [2][64][64]
    ushort_t* VsB = SM + 8192;        // [2][64][64]
    int sdst = wave * 1024;           // ushort offset of wave's 16-row region

    float l_part = 0.f;
    f32x16 o_acc[2];
    #pragma unroll
    for (int dg = 0; dg < 2; ++dg)
        #pragma unroll
        for (int i = 0; i < 16; ++i) o_acc[dg][i] = 0.f;

    // prologue: stage tile 0 into buf 0
    llds16(KsB + sdst, ksrc);
    llds16(KsB + sdst + 512, ksrc2);
    llds16(VsB + sdst, vsrc);
    llds16(VsB + sdst + 512, vsrc2);
    if (tid < 64) fgs[0][tid] = (fg[b * Lh + kb0 + tid] - 1.0f) * MSK2;

    for (int kt = 0; kt < 18; ++kt) {
        int cur = kt & 1, nxt = cur ^ 1;
        __syncthreads();

        if (kt + 1 < 18) {
            const ushort_t* kp  = ksrc  + (size_t)(kt + 1) * 64 * QS2;
            const ushort_t* kp2 = ksrc2 + (size_t)(kt + 1) * 64 * QS2;
            llds16(KsB + nxt * 4096 + sdst, kp);
            llds16(KsB + nxt * 4096 + sdst + 512, kp2);
            llds16(VsB + nxt * 4096 + sdst, vsrc + (kt + 1) * 64);
            llds16(VsB + nxt * 4096 + sdst + 512, vsrc2 + (kt + 1) * 64);
            if (tid < 64) fgs[nxt][tid] = (fg[b * Lh + kb0 + (kt + 1) * 64 + tid] - 1.0f) * MSK2;
        }

        #pragma unroll
        for (int kg = 0; kg < 2; ++kg) {
            // QK^T for keys kg*32..kg*32+31
            f32x16 sA;
            #pragma unroll
            for (int i = 0; i < 16; ++i) sA[i] = 0.f;
            #pragma unroll
            for (int kkg = 0; kkg < 4; ++kkg) {
                bf16x8 bk = *(const bf16x8*)&KsB[cur * 4096 + (kg * 32 + l31) * 64 +
                                                 (((kkg * 2 + hi) ^ (l31 & 7)) * 8)];
                sA = MFMA32(bk, aq[kkg], sA);
            }
            // masked exp2: key = kg*32 + 8*r4 + 4*hi + s -> float4 broadcast read
            float ev[16];
            #pragma unroll
            for (int r4 = 0; r4 < 4; ++r4) {
                float4 mb = *(const float4*)&fgs[cur][kg * 32 + 8 * r4 + 4 * hi];
                float e0 = EXP2F(sA[r4 * 4 + 0] * SCL2 + mb.x);
                float e1 = EXP2F(sA[r4 * 4 + 1] * SCL2 + mb.y);
                float e2 = EXP2F(sA[r4 * 4 + 2] * SCL2 + mb.z);
                float e3 = EXP2F(sA[r4 * 4 + 3] * SCL2 + mb.w);
                ev[r4 * 4 + 0] = e0; ev[r4 * 4 + 1] = e1;
                ev[r4 * 4 + 2] = e2; ev[r4 * 4 + 3] = e3;
                l_part += (e0 + e1) + (e2 + e3);
            }
            // pack P into PV B-operand fragments (two 16-key tiles per kg)
            #pragma unroll
            for (int th = 0; th < 2; ++th) {
                int t16 = kg * 2 + th;
                uint_t w0 = cvtpk(ev[8 * th + 0], ev[8 * th + 1]);
                uint_t w1 = cvtpk(ev[8 * th + 2], ev[8 * th + 3]);
                uint_t w2 = cvtpk(ev[8 * th + 4], ev[8 * th + 5]);
                uint_t w3 = cvtpk(ev[8 * th + 6], ev[8 * th + 7]);
                plswap(w0, w2);
                plswap(w1, w3);
                union { uint_t u[4]; bf16x8 v; } pw;
                pw.u[0] = w0; pw.u[1] = w1; pw.u[2] = w2; pw.u[3] = w3;
                #pragma unroll
                for (int dg = 0; dg < 2; ++dg) {
                    bf16x8 bv = *(const bf16x8*)&VsB[cur * 4096 + (dg * 32 + l31) * 64 +
                                                     (((t16 * 2 + hi) ^ (l31 & 7)) * 8)];
                    o_acc[dg] = MFMA32(bv, pw.v, o_acc[dg]);
                }
            }
        }
    }

    // partial outputs: unnormalized o (f32) + l per (q,h)
    float lsum = l_part + __shfl_xor(l_part, 32, 64);
    float* op = Opart + ((size_t)half * 4608 + b * Lh + tok_q) * Ch + h * 64 + hi * 4;
    #pragma unroll
    for (int dg = 0; dg < 2; ++dg)
        #pragma unroll
        for (int r4 = 0; r4 < 4; ++r4) {
            *(float4*)(op + dg * 32 + r4 * 8) =
                make_float4(o_acc[dg][r4 * 4 + 0], o_acc[dg][r4 * 4 + 1],
                            o_acc[dg][r4 * 4 + 2], o_acc[dg][r4 * 4 + 3]);
        }
    if (hi == 0)
        Lpart[((size_t)half * 4608 + b * Lh + tok_q) * NHh + h] = lsum;
}

__device__ __forceinline__ void attn_local_body(
    const ushort_t* __restrict__ QKV, const ushort_t* __restrict__ VT,
    ushort_t* __restrict__ O, int tile, int h, int b,
    ushort_t (*Ks)[2][64][32], ushort_t (*Vs)[2][64][32], ushort_t (*Ps)[72])
{
    int tid = threadIdx.x;
    int lane = tid & 63;
    int wave = tid >> 6;
    int quad = lane >> 4, l15 = lane & 15;
    int wi = tile / 6, wj = tile % 6;

    bf16x8 aq[2];
    {
        int ql = wave * 16 + l15;
        int tok = (wi * 8 + (ql >> 3)) * 48 + wj * 8 + (ql & 7);
        const ushort_t* qbase = QKV + (size_t)(b * Lh + tok) * QS2 + 1536 + h * 64;
        #pragma unroll
        for (int step = 0; step < 2; ++step)
            aq[step] = *(const bf16x8*)(qbase + step * 32 + quad * 8);
    }

    // staging: K rows = window tokens; V rows = d, chunks = token-groups
    {
        int srow = lane >> 2;
        int sc = lane & 3;
        int krow = wave * 16 + srow;
        int kfs = (krow >> 1) & 3;
        int tokK = (wi * 8 + (krow >> 3)) * 48 + wj * 8 + (krow & 7);
        const ushort_t* ksrc = QKV + (size_t)(b * Lh + tokK) * QS2 + 2304 + h * 64 + (sc ^ kfs) * 8;
        int c0 = sc ^ kfs;
        const ushort_t* vbase = VT + (size_t)(768 + h * 64 + krow) * 4608 + b * Lh + wj * 8;
        llds16(&Ks[0][0][wave * 16][0], ksrc);
        llds16(&Ks[0][1][wave * 16][0], ksrc + 32);
        llds16(&Vs[0][0][wave * 16][0], vbase + (wi * 8 + c0) * 48);
        llds16(&Vs[0][1][wave * 16][0], vbase + (wi * 8 + 4 + c0) * 48);
    }
    __syncthreads();

    float l_part = 0.f;
    f32x4 o_acc[4];
    #pragma unroll
    for (int t4 = 0; t4 < 4; ++t4) o_acc[t4] = (f32x4){0.f, 0.f, 0.f, 0.f};

    int rfs = (l15 >> 1) & 3;
    f32x4 s4[4];
    #pragma unroll
    for (int j4 = 0; j4 < 4; ++j4) s4[j4] = (f32x4){0.f, 0.f, 0.f, 0.f};
    #pragma unroll
    for (int step = 0; step < 2; ++step) {
        bf16x8 bk[4];
        #pragma unroll
        for (int j4 = 0; j4 < 4; ++j4)
            bk[j4] = *(const bf16x8*)&Ks[0][step][j4 * 16 + l15][(quad ^ rfs) * 8];
        #pragma unroll
        for (int j4 = 0; j4 < 4; ++j4)
            s4[j4] = MFMA16(bk[j4], aq[step], s4[j4]);
    }
    int p0 = wave * 16;
    #pragma unroll
    for (int j4 = 0; j4 < 4; ++j4) {
        float e0 = EXP2F(s4[j4][0] * SCL2);
        float e1 = EXP2F(s4[j4][1] * SCL2);
        float e2 = EXP2F(s4[j4][2] * SCL2);
        float e3 = EXP2F(s4[j4][3] * SCL2);
        l_part += (e0 + e1) + (e2 + e3);
        uint_t a01 = __builtin_amdgcn_perm(__float_as_uint(e1), __float_as_uint(e0), 0x07060302u);
        uint_t a23 = __builtin_amdgcn_perm(__float_as_uint(e3), __float_as_uint(e2), 0x07060302u);
        *(uint2*)&Ps[p0 + l15][j4 * 16 + quad * 4] = make_uint2(a01, a23);
    }
    #pragma unroll
    for (int step = 0; step < 2; ++step) {
        bf16x8 bv[4];
        #pragma unroll
        for (int t4 = 0; t4 < 4; ++t4)
            bv[t4] = *(const bf16x8*)&Vs[0][step][t4 * 16 + l15][(quad ^ rfs) * 8];
        bf16x8 a = *(const bf16x8*)&Ps[p0 + l15][step * 32 + quad * 8];
        #pragma unroll
        for (int t4 = 0; t4 < 4; ++t4)
            o_acc[t4] = MFMA16(bv[t4], a, o_acc[t4]);   // swapped: lane=q
    }

    {
        float v = l_part;
        v += __shfl_xor(v, 16, 64);
        v += __shfl_xor(v, 32, 64);
        float inv = 1.0f / v;
        int ql = wave * 16 + l15;
        int tok = (wi * 8 + (ql >> 3)) * 48 + wj * 8 + (ql & 7);
        ushort_t* ob = O + (size_t)(b * Lh + tok) * Ch + h * 64;
        #pragma unroll
        for (int t4 = 0; t4 < 4; ++t4) {
            *(uint2*)&ob[t4 * 16 + quad * 4] =
                make_uint2(pack2bf(o_acc[t4][0] * inv, o_acc[t4][1] * inv),
                           pack2bf(o_acc[t4][2] * inv, o_acc[t4][3] * inv));
        }
    }
}

__global__ __launch_bounds__(256)
void attn_fused_kernel(const ushort_t* __restrict__ QKV, const ushort_t* __restrict__ VT,
                       const float* __restrict__ fg,
                       float* __restrict__ Opart, float* __restrict__ Lpart,
                       ushort_t* __restrict__ ctxl)
{
    // 32 KB shared pool: global uses K[2][64][64] + V[2][64][64];
    // local carves K(8K) + V(8K) + Ps(9.2K) from the same pool.
    __shared__ __align__(16) ushort_t SM[16384];
    __shared__ float fgs[2][64];

    int bid = blockIdx.x;
    if (bid < 864) {
        // bijective XCD swizzle: 108 consecutive logical blocks per XCD
        int gid = (bid & 7) * 108 + (bid >> 3);
        int half = gid / 432;
        int rem = gid % 432;
        int tile = rem % 18;
        int h = (rem / 18) % NHh;
        int b = rem / 216;
        attn_global_body(QKV, VT, fg, Opart, Lpart, tile, h, b, half, SM, fgs);
    } else {
        int rr = bid - 864;
        int lid = (rr & 7) * 108 + (rr >> 3);
        int tile = lid % 36;
        int h = (lid / 36) % NHh;
        int b = lid / 432;
        attn_local_body(QKV, VT, ctxl, tile, h, b,
                        (ushort_t(*)[2][64][32])SM,
                        (ushort_t(*)[2][64][32])(SM + 4096),
                        (ushort_t(*)[72])(SM + 8192));
    }
}

// ---------------------------------------------------------------- split-KV merge
// ctxg[r][d] = (Oa[r][d] + Ob[r][d]) / (La[r][h] + Lb[r][h]), bf16 out
__global__ __launch_bounds__(192)
void attn_merge_kernel(const float* __restrict__ Op, const float* __restrict__ Lp,
                       ushort_t* __restrict__ ctxg)
{
    int r = blockIdx.x;
    int tid = threadIdx.x;
    int d = tid * 4;
    int h = d >> 6;
    float la = Lp[(size_t)r * NHh + h];
    float lb = Lp[((size_t)4608 + r) * NHh + h];
    float inv = 1.0f / (la + lb);
    const float* pa = Op + (size_t)r * Ch + d;
    const float* pb = Op + (size_t)4608 * Ch + (size_t)r * Ch + d;
    float4 a = *(const float4*)pa;
    float4 b4 = *(const float4*)pb;
    *(uint2*)&ctxg[(size_t)r * Ch + d] =
        make_uint2(pack2bf((a.x + b4.x) * inv, (a.y + b4.y) * inv),
                   pack2bf((a.z + b4.z) * inv, (a.w + b4.w) * inv));
}

// ---------------------------------------------------------------- launch
extern "C" void kernel_launch(void* const* d_in, const int* in_sizes, int n_in,
                              void* d_out, int out_size, void* d_ws, size_t ws_size,
                              hipStream_t stream)
{
    const float* x       = (const float*)d_in[0];
    const float* mask    = (const float*)d_in[1];
    const float* w_qkv_g = (const float*)d_in[2];
    const float* b_qkv_g = (const float*)d_in[3];
    const float* w_o_g   = (const float*)d_in[4];
    const float* b_o_g   = (const float*)d_in[5];
    const float* w_qkv_l = (const float*)d_in[6];
    const float* b_qkv_l = (const float*)d_in[7];
    const float* w_o_l   = (const float*)d_in[8];
    const float* b_o_l   = (const float*)d_in[9];
    const float* ln1_w   = (const float*)d_in[10];
    const float* ln1_b   = (const float*)d_in[11];
    const float* ln2_w   = (const float*)d_in[12];
    const float* ln2_b   = (const float*)d_in[13];
    const float* w_fc1   = (const float*)d_in[14];
    const float* b_fc1   = (const float*)d_in[15];
    const float* w_fc2   = (const float*)d_in[16];
    const float* b_fc2   = (const float*)d_in[17];
    float* out = (float*)d_out;

    const size_t U = (size_t)Bh * Lh * Ch;           // 3,538,944
    char* p = (char*)d_ws;
    ushort_t* qkvb = (ushort_t*)p;        p += (size_t)4608 * 3072 * 2;  // [4608][qg|kg|ql|kl]
    ushort_t* vtb  = (ushort_t*)p;        p += (size_t)1536 * 4608 * 2;  // V^T [col'][token]
    ushort_t* midb = qkvb;                                               // [4608][3072] aliases
    ushort_t* ctxg = (ushort_t*)p;        p += U * 2;
    ushort_t* ctxl = (ushort_t*)p;        p += U * 2;
    ushort_t* xnb  = (ushort_t*)p;        p += U * 2;
    float*    Opart = (float*)p;          p += (size_t)2 * U * 4;        // f32 partials (2 halves)
    float*    Lpart = (float*)p;          p += (size_t)2 * 4608 * NHh * 4;
    float*    x1   = Opart;               // alias: x1 live only after merge consumed Opart
    ushort_t* wtq  = (ushort_t*)p;        p += (size_t)4608 * 768 * 2;   // qkv g|l concat
    ushort_t* wt_o_g = (ushort_t*)p;      p += (size_t)768 * 768 * 2;
    ushort_t* wt_o_l = (ushort_t*)p;      p += (size_t)768 * 768 * 2;
    ushort_t* wt_fc1 = (ushort_t*)p;      p += (size_t)3072 * 768 * 2;
    ushort_t* wt_fc2 = (ushort_t*)p;      p += (size_t)768 * 3072 * 2;
    float*    biasq  = (float*)p;         p += 4608 * 4;
    float*    fg     = (float*)p;         p += Bh * Lh * 4;
    float*    bgw    = (float*)p;

    const int Mrows = Bh * Lh;                   // 4608
    dim3 blk(256);

    // weights + biases (blocks 2304/2305 copy biasq)
    transpose_all_kernel<<<2306, blk, 0, stream>>>(
        w_qkv_g, w_qkv_l, w_o_g, w_o_l, w_fc1, w_fc2, b_qkv_g, b_qkv_l,
        wtq, wt_o_g, wt_o_l, wt_fc1, wt_fc2, biasq);

    // ln1 + mask fused (blocks 4608..4679 do the mask windows)
    ln_mask_kernel<<<4680, blk, 0, stream>>>(x, ln1_w, ln1_b, xnb, mask, fg, bgw);

    // QKV GEMM: one dispatch, bx<24 = Q|K tiles, bx>=24 = V tiles (V^T out)
    qkv_gemm_kernel<<<dim3(36, Mrows / 128), blk, 0, stream>>>(
        xnb, wtq, biasq, qkvb, vtb);

    // fused attention: 864 global split-KV blocks (32x32 path) + 864 local blocks
    attn_fused_kernel<<<1728, blk, 0, stream>>>(qkvb, vtb, fg, Opart, Lpart, ctxl);
    attn_merge_kernel<<<Mrows, dim3(192), 0, stream>>>(Opart, Lpart, ctxg);

    // dual masked o-projection -> x1 (one fused dispatch, single K-loop)
    oproj_dual_kernel<<<dim3(Ch / 64, Mrows / 128), blk, 0, stream>>>(
        ctxg, ctxl, wt_o_g, wt_o_l, b_o_g, b_o_l, x, x1, fg, bgw);

    layernorm_bf16_kernel<<<Mrows, blk, 0, stream>>>(x1, ln2_w, ln2_b, xnb);

    // MLP
    gemm_bf16_t<128><<<dim3(3072 / 128, Mrows / 128), blk, 0, stream>>>(
        xnb, wt_fc1, b_fc1, nullptr, midb, Mrows, 3072, Ch, 1 | 2);
    gemm_bf16_t<64><<<dim3(Ch / 64, Mrows / 128), blk, 0, stream>>>(
        midb, wt_fc2, b_fc2, x1, out, Mrows, Ch, 3072, 0);
}

// Round 10
// 392.087 us; speedup vs baseline: 1.0429x; 1.0096x over previous
//
#include <hip/hip_runtime.h>
#include <math.h>

#define Lh 2304
#define Ch 768
#define NHh 12
#define Bh 2
#define QS2 3072  // row stride of packed qkv activation buffer [qg|kg|ql|kl]

typedef unsigned short ushort_t;
typedef unsigned int uint_t;
typedef __attribute__((ext_vector_type(8))) short bf16x8;
typedef __attribute__((ext_vector_type(4))) float f32x4;
#define MFMA16(a, b, c) __builtin_amdgcn_mfma_f32_16x16x32_bf16(a, b, c, 0, 0, 0)

// softmax in exp2 domain: exp(s*0.125 + m) == exp2(s*SCL2 + m*log2e)  (R1-validated)
#define SCL2 0.18033688f        // 0.125 * log2(e)
#define MSK2 1.4426950e9f       // 1e9  * log2(e)
#if __has_builtin(__builtin_amdgcn_exp2f)
#define EXP2F(x) __builtin_amdgcn_exp2f(x)
#else
#define EXP2F(x) exp2f(x)
#endif

__device__ __forceinline__ ushort_t f2bf(float f) {
    union { float f; uint_t u; } v; v.f = f;
    uint_t u = v.u + 0x7fffu + ((v.u >> 16) & 1u);   // RNE
    return (ushort_t)(u >> 16);
}
// pack 2 fp32 -> 2 bf16 (RNE) into one u32
__device__ __forceinline__ uint_t pack2bf(float a, float b) {
    return (uint_t)f2bf(a) | ((uint_t)f2bf(b) << 16);
}

// async global->LDS, 16B/lane, dest = wave-uniform base + lane*16
__device__ __forceinline__ void llds16(ushort_t* dst, const ushort_t* src) {
    __builtin_amdgcn_global_load_lds(
        (__attribute__((address_space(1))) void*)(const_cast<ushort_t*>(src)),
        (__attribute__((address_space(3))) void*)dst, 16, 0, 0);
}

// ---------------------------------------------------------------- layernorm (fp32 in, bf16 out)
__device__ __forceinline__ void ln_body(const float* __restrict__ x, const float* __restrict__ w,
                                        const float* __restrict__ b, ushort_t* __restrict__ y,
                                        int row, float* red)
{
    int tid = threadIdx.x;
    const float* xr = x + (size_t)row * Ch;
    float v0 = xr[tid], v1 = xr[tid + 256], v2 = xr[tid + 512];
    red[tid] = v0 + v1 + v2;
    __syncthreads();
    for (int st = 128; st > 0; st >>= 1) {
        if (tid < st) red[tid] += red[tid + st];
        __syncthreads();
    }
    float mean = red[0] * (1.0f / 768.0f);
    __syncthreads();
    float d0 = v0 - mean, d1 = v1 - mean, d2 = v2 - mean;
    red[tid] = d0 * d0 + d1 * d1 + d2 * d2;
    __syncthreads();
    for (int st = 128; st > 0; st >>= 1) {
        if (tid < st) red[tid] += red[tid + st];
        __syncthreads();
    }
    float rstd = rsqrtf(red[0] * (1.0f / 768.0f) + 1e-6f);
    ushort_t* yr = y + (size_t)row * Ch;
    yr[tid]       = f2bf(d0 * rstd * w[tid]       + b[tid]);
    yr[tid + 256] = f2bf(d1 * rstd * w[tid + 256] + b[tid + 256]);
    yr[tid + 512] = f2bf(d2 * rstd * w[tid + 512] + b[tid + 512]);
}

__global__ __launch_bounds__(256)
void layernorm_bf16_kernel(const float* __restrict__ x, const float* __restrict__ w,
                           const float* __restrict__ b, ushort_t* __restrict__ y)
{
    __shared__ float red[256];
    ln_body(x, w, b, y, blockIdx.x, red);
}

// ln1 + mask fused into one dispatch (block-uniform branch)
__global__ __launch_bounds__(256)
void ln_mask_kernel(const float* __restrict__ x, const float* __restrict__ w,
                    const float* __restrict__ b, ushort_t* __restrict__ y,
                    const float* __restrict__ mask, float* __restrict__ fg,
                    float* __restrict__ bgw)
{
    __shared__ float red[256];
    int bid = blockIdx.x;
    if (bid < 4608) {
        ln_body(x, w, b, y, bid, red);
        return;
    }
    int win = bid - 4608;            // 0..71
    int tid = threadIdx.x;
    if (tid >= 64) return;
    int bb = win / 36, ww = win % 36;
    int wi = ww / 6, wj = ww % 6;
    int i = wi * 8 + (tid >> 3), j = wj * 8 + (tid & 7);
    const float* mb = mask + (size_t)bb * 192 * 192 + (size_t)(i * 4) * 192 + j * 4;
    float s = 0.0f;
    #pragma unroll
    for (int di = 0; di < 4; ++di) {
        float4 v = *(const float4*)(mb + (size_t)di * 192);
        s += v.x + v.y + v.z + v.w;
    }
    float f = (s * (1.0f / 16.0f) > 0.4f) ? 1.0f : 0.0f;
    fg[bb * Lh + i * 48 + j] = f;
    unsigned long long bg = __ballot(f == 0.0f);
    if (tid == 0) bgw[win] = bg ? 1.0f : 0.0f;
}

// ---------------------------------------------------------------- batched weight cast+transpose
// blocks 2304/2305 copy the qkv biases; R20: float4 global loads (was 16
// scalar dword loads/thread; LDS stores stay scalar — [64][65] pad breaks
// b128 alignment)
__global__ __launch_bounds__(256)
void transpose_all_kernel(const float* __restrict__ w_qkv_g, const float* __restrict__ w_qkv_l,
                          const float* __restrict__ w_o_g, const float* __restrict__ w_o_l,
                          const float* __restrict__ w_fc1, const float* __restrict__ w_fc2,
                          const float* __restrict__ b_qkv_g, const float* __restrict__ b_qkv_l,
                          ushort_t* __restrict__ wtq, ushort_t* __restrict__ wt_o_g,
                          ushort_t* __restrict__ wt_o_l, ushort_t* __restrict__ wt_fc1,
                          ushort_t* __restrict__ wt_fc2, float* __restrict__ biasq)
{
    int blk = blockIdx.x;
    int tid = threadIdx.x;
    if (blk >= 2304) {
        int which = blk - 2304;
        const float* src = which ? b_qkv_l : b_qkv_g;
        float* dst = biasq + which * 2304;
        for (int i = tid; i < 2304; i += 256) dst[i] = src[i];
        return;
    }
    const float* W; ushort_t* D; int K, N, nx, bx;
    const size_t CC = (size_t)Ch * Ch;
    if (blk < 432)       { int t = blk / 144; bx = blk % 144;
                           W = w_qkv_g + t * CC; D = wtq + t * CC; K = 768; N = 768; nx = 12; }
    else if (blk < 864)  { int r = blk - 432; int t = r / 144; bx = r % 144;
                           W = w_qkv_l + t * CC; D = wtq + (size_t)2304 * 768 + t * CC;
                           K = 768; N = 768; nx = 12; }
    else if (blk < 1008) { bx = blk - 864;  W = w_o_g; D = wt_o_g; K = 768; N = 768; nx = 12; }
    else if (blk < 1152) { bx = blk - 1008; W = w_o_l; D = wt_o_l; K = 768; N = 768; nx = 12; }
    else if (blk < 1728) { bx = blk - 1152; W = w_fc1; D = wt_fc1; K = 768; N = 3072; nx = 48; }
    else                 { bx = blk - 1728; W = w_fc2; D = wt_fc2; K = 3072; N = 768; nx = 12; }
    int n0 = (bx % nx) * 64;
    int k0 = (bx / nx) * 64;
    __shared__ float T[64][65];
    #pragma unroll
    for (int i = 0; i < 4; ++i) {
        int lin = i * 256 + tid;          // 0..1023
        int r = lin >> 4, c = (lin & 15) * 4;
        float4 v = *(const float4*)&W[(size_t)(k0 + r) * N + n0 + c];
        T[r][c] = v.x; T[r][c + 1] = v.y; T[r][c + 2] = v.z; T[r][c + 3] = v.w;
    }
    __syncthreads();
    // vectorized: each unit = (n-row r, 4 consecutive k) -> one b64 store
    #pragma unroll
    for (int i = 0; i < 4; ++i) {
        int lin = i * 256 + tid;          // 0..1023
        int r = lin >> 4, c0 = (lin & 15) * 4;
        uint_t lo = pack2bf(T[c0][r], T[c0 + 1][r]);
        uint_t hi = pack2bf(T[c0 + 2][r], T[c0 + 3][r]);
        *(uint2*)&D[(size_t)(n0 + r) * K + k0 + c0] = make_uint2(lo, hi);
    }
}

// ---------------------------------------------------------------- bf16 MFMA GEMM body
// flags: 1=gelu, 2=bf16 out, 4=qkv split-store (packed [qg|kg|ql|kl], stride 3072)
// VMODE=1 = V column-tiles with unswapped MFMA -> acc lane = output col (d),
// quad*4+r = 4 consecutive tokens -> coalesced uint2 V^T stores. VMODE is a
// compile-time param; the QKV kernel branches between bodies at KERNEL TOP
// (R5 lesson: a runtime branch inside the K-loop breaks pipelining).
template<int BNt, int VMODE>
__device__ __forceinline__ void gemm_body(
    const ushort_t* __restrict__ A, const ushort_t* __restrict__ Bt,
    const float* __restrict__ bias, const float* __restrict__ residual,
    void* __restrict__ C, ushort_t* __restrict__ vt,
    int M, int N, int K, int flags, int bm, int bn, ushort_t* pool)
{
    ushort_t (*AsL)[128 * 32] = (ushort_t(*)[128 * 32])pool;
    ushort_t (*BsL)[BNt * 32] = (ushort_t(*)[BNt * 32])(pool + 2 * 128 * 32);
    int tid = threadIdx.x;
    int lane = tid & 63;
    int wave = tid >> 6;
    int wm = wave >> 1, wn = wave & 1;
    int quad = lane >> 4, l15 = lane & 15;
    constexpr int NJ = BNt / 32;

    int srow = lane >> 2;
    int sg8 = ((lane & 3) ^ ((lane >> 3) & 3)) * 8;
    int fsw = (l15 >> 1) & 3;

    f32x4 acc[4][NJ];
    #pragma unroll
    for (int i = 0; i < 4; ++i)
        #pragma unroll
        for (int j = 0; j < NJ; ++j)
            acc[i][j] = (f32x4){0.f, 0.f, 0.f, 0.f};

    int iters = K / 32;
    llds16(&AsL[0][wave * 512], A + (size_t)(bm + wave * 16 + srow) * K + sg8);
    llds16(&AsL[0][(wave + 4) * 512], A + (size_t)(bm + (wave + 4) * 16 + srow) * K + sg8);
    llds16(&BsL[0][wave * 512], Bt + (size_t)(bn + wave * 16 + srow) * K + sg8);
    if (BNt == 128)
        llds16(&BsL[0][(wave + 4) * 512], Bt + (size_t)(bn + (wave + 4) * 16 + srow) * K + sg8);

    for (int kt = 0; kt < iters; ++kt) {
        int cur = kt & 1;
        __syncthreads();

        bf16x8 af[4], bfr[NJ];
        #pragma unroll
        for (int i = 0; i < 4; ++i)
            af[i] = *(const bf16x8*)&AsL[cur][(wm * 64 + i * 16 + l15) * 32 + ((quad ^ fsw) * 8)];
        #pragma unroll
        for (int j = 0; j < NJ; ++j)
            bfr[j] = *(const bf16x8*)&BsL[cur][(wn * (BNt / 2) + j * 16 + l15) * 32 + ((quad ^ fsw) * 8)];

        if (kt + 1 < iters) {
            int k0 = (kt + 1) * 32;
            int nxt = 1 - cur;
            llds16(&AsL[nxt][wave * 512], A + (size_t)(bm + wave * 16 + srow) * K + k0 + sg8);
            llds16(&AsL[nxt][(wave + 4) * 512], A + (size_t)(bm + (wave + 4) * 16 + srow) * K + k0 + sg8);
            llds16(&BsL[nxt][wave * 512], Bt + (size_t)(bn + wave * 16 + srow) * K + k0 + sg8);
            if (BNt == 128)
                llds16(&BsL[nxt][(wave + 4) * 512], Bt + (size_t)(bn + (wave + 4) * 16 + srow) * K + k0 + sg8);
        }

        if constexpr (VMODE == 0) {
            // swapped operands: lane = A row (output row), quad*4+r = B row (output col)
            #pragma unroll
            for (int i = 0; i < 4; ++i)
                #pragma unroll
                for (int j = 0; j < NJ; ++j)
                    acc[i][j] = MFMA16(bfr[j], af[i], acc[i][j]);
        } else {
            // unswapped: lane = B row (output col/d), quad*4+r = A row (token)
            #pragma unroll
            for (int i = 0; i < 4; ++i)
                #pragma unroll
                for (int j = 0; j < NJ; ++j)
                    acc[i][j] = MFMA16(af[i], bfr[j], acc[i][j]);
        }
    }

    if constexpr (VMODE == 1) {
        #pragma unroll
        for (int j = 0; j < NJ; ++j) {
            int col = bn + wn * (BNt / 2) + j * 16 + l15;
            int colp = col - ((col >= 3840) ? 3072 : 1536);
            float bc = bias[col];
            #pragma unroll
            for (int i = 0; i < 4; ++i) {
                int row0 = bm + wm * 64 + i * 16 + quad * 4;
                *(uint2*)&vt[(size_t)colp * 4608 + row0] =
                    make_uint2(pack2bf(acc[i][j][0] + bc, acc[i][j][1] + bc),
                               pack2bf(acc[i][j][2] + bc, acc[i][j][3] + bc));
            }
        }
        return;
    }

    #pragma unroll
    for (int i = 0; i < 4; ++i) {
        int row = bm + wm * 64 + i * 16 + l15;
        #pragma unroll
        for (int j = 0; j < NJ; ++j) {
            int col = bn + wn * (BNt / 2) + j * 16 + quad * 4;
            float4 bia = *(const float4*)&bias[col];
            float o0 = acc[i][j][0] + bia.x;
            float o1 = acc[i][j][1] + bia.y;
            float o2 = acc[i][j][2] + bia.z;
            float o3 = acc[i][j][3] + bia.w;
            if (flags & 1) {
                o0 = o0 * 0.5f * (1.0f + erff(o0 * 0.70710678f));
                o1 = o1 * 0.5f * (1.0f + erff(o1 * 0.70710678f));
                o2 = o2 * 0.5f * (1.0f + erff(o2 * 0.70710678f));
                o3 = o3 * 0.5f * (1.0f + erff(o3 * 0.70710678f));
            }
            if (residual) {
                float4 rs = *(const float4*)&residual[(size_t)row * N + col];
                o0 += rs.x; o1 += rs.y; o2 += rs.z; o3 += rs.w;
            }
            if (flags & 4) {
                int cq = col - ((col >= 2304) ? 768 : 0);
                *(uint2*)&((ushort_t*)C)[(size_t)row * QS2 + cq] =
                    make_uint2(pack2bf(o0, o1), pack2bf(o2, o3));
            } else if (flags & 2) {
                *(uint2*)&((ushort_t*)C)[(size_t)row * N + col] =
                    make_uint2(pack2bf(o0, o1), pack2bf(o2, o3));
            } else {
                *(float4*)&((float*)C)[(size_t)row * N + col] =
                    make_float4(o0, o1, o2, o3);
            }
        }
    }
}

template<int BNt>
__global__ __launch_bounds__(256)
void gemm_bf16_t(const ushort_t* __restrict__ A, const ushort_t* __restrict__ Bt,
                 const float* __restrict__ bias, const float* __restrict__ residual,
                 void* __restrict__ C, int M, int N, int K, int flags)
{
    __shared__ ushort_t pool[2 * 128 * 32 + 2 * BNt * 32];
    gemm_body<BNt, 0>(A, Bt, bias, residual, C, nullptr, M, N, K, flags,
                      blockIdx.y * 128, blockIdx.x * BNt, pool);
}

// single QKV dispatch; bx<24 = Q|K tiles (VMODE 0), bx>=24 = V tiles
// (VMODE 1, V^T out). Top-level branch (two disjoint inlined bodies).
__global__ __launch_bounds__(256)
void qkv_gemm_kernel(const ushort_t* __restrict__ A, const ushort_t* __restrict__ Bt,
                     const float* __restrict__ biasq, ushort_t* __restrict__ qkv,
                     ushort_t* __restrict__ vt)
{
    __shared__ ushort_t pool[4 * 128 * 32];
    int bx = blockIdx.x;
    int bm = blockIdx.y * 128;
    if (bx < 24) {
        int bn = (bx < 12) ? bx * 128 : 2304 + (bx - 12) * 128;
        gemm_body<128, 0>(A, Bt, biasq, nullptr, qkv, nullptr, 4608, 4608, Ch, 4, bm, bn, pool);
    } else {
        int bxx = bx - 24;
        int bn = (bxx < 6) ? 1536 + bxx * 128 : 3840 + (bxx - 6) * 128;
        gemm_body<128, 1>(A, Bt, biasq, nullptr, nullptr, vt, 4608, 4608, Ch, 4, bm, bn, pool);
    }
}

// ---------------------------------------------------------------- dual o-projection
// single fused 24-kt loop staging all four tiles (Ag, Al, Bg, Bl) ->
// 16 MFMAs per barrier. LDS 48 KB.
__global__ __launch_bounds__(256)
void oproj_dual_kernel(const ushort_t* __restrict__ ctxg, const ushort_t* __restrict__ ctxl,
                       const ushort_t* __restrict__ Wg, const ushort_t* __restrict__ Wl,
                       const float* __restrict__ biasg, const float* __restrict__ biasl,
                       const float* __restrict__ x, float* __restrict__ x1,
                       const float* __restrict__ fg, const float* __restrict__ bgw)
{
    __shared__ ushort_t AgL[2][128 * 32];
    __shared__ ushort_t AlL[2][128 * 32];
    __shared__ ushort_t BgL[2][64 * 32];
    __shared__ ushort_t BlL[2][64 * 32];
    int bm = blockIdx.y * 128;
    int bn = blockIdx.x * 64;
    int tid = threadIdx.x;
    int lane = tid & 63;
    int wave = tid >> 6;
    int wm = wave >> 1, wn = wave & 1;
    int quad = lane >> 4, l15 = lane & 15;

    int srow = lane >> 2;
    int sg8 = ((lane & 3) ^ ((lane >> 3) & 3)) * 8;
    int fsw = (l15 >> 1) & 3;
    const int K = Ch, N = Ch, iters = Ch / 32;

    f32x4 accg[4][2], accl[4][2];
    #pragma unroll
    for (int i = 0; i < 4; ++i)
        #pragma unroll
        for (int j = 0; j < 2; ++j) {
            accg[i][j] = (f32x4){0.f, 0.f, 0.f, 0.f};
            accl[i][j] = (f32x4){0.f, 0.f, 0.f, 0.f};
        }

    llds16(&AgL[0][wave * 512], ctxg + (size_t)(bm + wave * 16 + srow) * K + sg8);
    llds16(&AgL[0][(wave + 4) * 512], ctxg + (size_t)(bm + (wave + 4) * 16 + srow) * K + sg8);
    llds16(&AlL[0][wave * 512], ctxl + (size_t)(bm + wave * 16 + srow) * K + sg8);
    llds16(&AlL[0][(wave + 4) * 512], ctxl + (size_t)(bm + (wave + 4) * 16 + srow) * K + sg8);
    llds16(&BgL[0][wave * 512], Wg + (size_t)(bn + wave * 16 + srow) * K + sg8);
    llds16(&BlL[0][wave * 512], Wl + (size_t)(bn + wave * 16 + srow) * K + sg8);

    for (int kt = 0; kt < iters; ++kt) {
        int cur = kt & 1;
        __syncthreads();
        bf16x8 afg[4], afl[4], bfg[2], bfl[2];
        #pragma unroll
        for (int i = 0; i < 4; ++i) {
            afg[i] = *(const bf16x8*)&AgL[cur][(wm * 64 + i * 16 + l15) * 32 + ((quad ^ fsw) * 8)];
            afl[i] = *(const bf16x8*)&AlL[cur][(wm * 64 + i * 16 + l15) * 32 + ((quad ^ fsw) * 8)];
        }
        #pragma unroll
        for (int j = 0; j < 2; ++j) {
            bfg[j] = *(const bf16x8*)&BgL[cur][(wn * 32 + j * 16 + l15) * 32 + ((quad ^ fsw) * 8)];
            bfl[j] = *(const bf16x8*)&BlL[cur][(wn * 32 + j * 16 + l15) * 32 + ((quad ^ fsw) * 8)];
        }
        if (kt + 1 < iters) {
            int k0 = (kt + 1) * 32;
            int nxt = 1 - cur;
            llds16(&AgL[nxt][wave * 512], ctxg + (size_t)(bm + wave * 16 + srow) * K + k0 + sg8);
            llds16(&AgL[nxt][(wave + 4) * 512], ctxg + (size_t)(bm + (wave + 4) * 16 + srow) * K + k0 + sg8);
            llds16(&AlL[nxt][wave * 512], ctxl + (size_t)(bm + wave * 16 + srow) * K + k0 + sg8);
            llds16(&AlL[nxt][(wave + 4) * 512], ctxl + (size_t)(bm + (wave + 4) * 16 + srow) * K + k0 + sg8);
            llds16(&BgL[nxt][wave * 512], Wg + (size_t)(bn + wave * 16 + srow) * K + k0 + sg8);
            llds16(&BlL[nxt][wave * 512], Wl + (size_t)(bn + wave * 16 + srow) * K + k0 + sg8);
        }
        #pragma unroll
        for (int i = 0; i < 4; ++i)
            #pragma unroll
            for (int j = 0; j < 2; ++j)
                accg[i][j] = MFMA16(bfg[j], afg[i], accg[i][j]);
        #pragma unroll
        for (int i = 0; i < 4; ++i)
            #pragma unroll
            for (int j = 0; j < 2; ++j)
                accl[i][j] = MFMA16(bfl[j], afl[i], accl[i][j]);
    }

    #pragma unroll
    for (int i = 0; i < 4; ++i) {
        int row = bm + wm * 64 + i * 16 + l15;
        int bb = (row >= Lh) ? 1 : 0;
        int n = row - bb * Lh;
        int ii = n / 48, jj = n % 48;
        float keepg = (fg[row] != 0.0f) ? 1.0f : 0.0f;
        float keepl = (keepg == 0.0f &&
                       bgw[bb * 36 + (ii >> 3) * 6 + (jj >> 3)] != 0.0f) ? 1.0f : 0.0f;
        #pragma unroll
        for (int j = 0; j < 2; ++j) {
            int col = bn + wn * 32 + j * 16 + quad * 4;
            float4 bg4 = *(const float4*)&biasg[col];
            float4 bl4 = *(const float4*)&biasl[col];
            float4 x4 = *(const float4*)&x[(size_t)row * N + col];
            float4 o;
            o.x = x4.x + keepg * (accg[i][j][0] + bg4.x) + keepl * (accl[i][j][0] + bl4.x);
            o.y = x4.y + keepg * (accg[i][j][1] + bg4.y) + keepl * (accl[i][j][1] + bl4.y);
            o.z = x4.z + keepg * (accg[i][j][2] + bg4.z) + keepl * (accl[i][j][2] + bl4.z);
            o.w = x4.w + keepg * (accg[i][j][3] + bg4.w) + keepl * (accl[i][j][3] + bl4.w);
            *(float4*)&x1[(size_t)row * N + col] = o;
        }
    }
}

// ---------------------------------------------------------------- fused attention (global + local)
// R20: global body reverted to the R6-measured-best 16x16 variant (63.0 µs):
// llds16 K/V staging in GEMM layout, Ps LDS round-trip, fgs dbuf mask table,
// split-KV (18 kt/block), NO setprio. (R7 setprio = +2; R8/R9 32x32 in-reg-P
// = +3..+7 — both reverted per measurement.)
__device__ __forceinline__ void attn_global_body(
    const ushort_t* __restrict__ QKV, const ushort_t* __restrict__ VT,
    const float* __restrict__ fg,
    float* __restrict__ Opart, float* __restrict__ Lpart,
    int tile, int h, int b, int half,
    ushort_t (*Ks)[2][64][32], ushort_t (*Vs)[2][64][32],
    ushort_t (*Ps)[72], float (*fgs)[64])
{
    int tid = threadIdx.x;
    int lane = tid & 63;
    int wave = tid >> 6;
    int quad = lane >> 4, l15 = lane & 15;
    int kb0 = half * 1152;            // key-token base for this half

    bf16x8 aq[2][2];
    #pragma unroll
    for (int s = 0; s < 2; ++s) {
        int tok = tile * 128 + wave * 32 + s * 16 + l15;
        const ushort_t* qbase = QKV + (size_t)(b * Lh + tok) * QS2 + h * 64;
        #pragma unroll
        for (int step = 0; step < 2; ++step)
            aq[s][step] = *(const bf16x8*)(qbase + step * 32 + quad * 8);
    }

    // staging source pointers (per-lane, tile 0): row = wave*16 + (lane>>2),
    // chunk (lane&3) holds logical chunk (lane&3)^fsw(row) -> read undoes XOR
    int srow = lane >> 2;
    int sc = lane & 3;
    int krow = wave * 16 + srow;
    int scx = (sc ^ ((krow >> 1) & 3)) * 8;
    const ushort_t* ksrc = QKV + (size_t)(b * Lh + kb0 + krow) * QS2 + 768 + h * 64 + scx;
    const ushort_t* vsrc = VT + (size_t)(h * 64 + krow) * 4608 + b * Lh + kb0 + scx;

    float l_part[2] = {0.f, 0.f};
    f32x4 o_acc[2][4];
    #pragma unroll
    for (int s = 0; s < 2; ++s)
        #pragma unroll
        for (int t4 = 0; t4 < 4; ++t4) o_acc[s][t4] = (f32x4){0.f, 0.f, 0.f, 0.f};

    // prologue: stage tile 0 into buf 0
    llds16(&Ks[0][0][wave * 16][0], ksrc);
    llds16(&Ks[0][1][wave * 16][0], ksrc + 32);
    llds16(&Vs[0][0][wave * 16][0], vsrc);
    llds16(&Vs[0][1][wave * 16][0], vsrc + 32);
    if (tid < 64) fgs[0][tid] = (fg[b * Lh + kb0 + tid] - 1.0f) * MSK2;

    int rfs = (l15 >> 1) & 3;

    for (int kt = 0; kt < 18; ++kt) {
        int cur = kt & 1, nxt = cur ^ 1;
        __syncthreads();

        bf16x8 bk[2][4];
        #pragma unroll
        for (int step = 0; step < 2; ++step)
            #pragma unroll
            for (int j4 = 0; j4 < 4; ++j4)
                bk[step][j4] = *(const bf16x8*)&Ks[cur][step][j4 * 16 + l15][(quad ^ rfs) * 8];

        if (kt + 1 < 18) {
            const ushort_t* kp = ksrc + (size_t)(kt + 1) * 64 * QS2;
            const ushort_t* vp = vsrc + (kt + 1) * 64;
            llds16(&Ks[nxt][0][wave * 16][0], kp);
            llds16(&Ks[nxt][1][wave * 16][0], kp + 32);
            llds16(&Vs[nxt][0][wave * 16][0], vp);
            llds16(&Vs[nxt][1][wave * 16][0], vp + 32);
            if (tid < 64) fgs[nxt][tid] = (fg[b * Lh + kb0 + (kt + 1) * 64 + tid] - 1.0f) * MSK2;
        }

        f32x4 s4[2][4];
        #pragma unroll
        for (int s = 0; s < 2; ++s)
            #pragma unroll
            for (int j4 = 0; j4 < 4; ++j4) s4[s][j4] = (f32x4){0.f, 0.f, 0.f, 0.f};
        #pragma unroll
        for (int step = 0; step < 2; ++step)
            #pragma unroll
            for (int s = 0; s < 2; ++s)
                #pragma unroll
                for (int j4 = 0; j4 < 4; ++j4)
                    s4[s][j4] = MFMA16(bk[step][j4], aq[s][step], s4[s][j4]);

        #pragma unroll
        for (int s = 0; s < 2; ++s) {
            int p0 = wave * 32 + s * 16;
            #pragma unroll
            for (int j4 = 0; j4 < 4; ++j4) {
                float4 mb4 = *(const float4*)&fgs[cur][j4 * 16 + quad * 4];
                float e0 = EXP2F(s4[s][j4][0] * SCL2 + mb4.x);
                float e1 = EXP2F(s4[s][j4][1] * SCL2 + mb4.y);
                float e2 = EXP2F(s4[s][j4][2] * SCL2 + mb4.z);
                float e3 = EXP2F(s4[s][j4][3] * SCL2 + mb4.w);
                l_part[s] += (e0 + e1) + (e2 + e3);
                uint_t a01 = __builtin_amdgcn_perm(__float_as_uint(e1), __float_as_uint(e0), 0x07060302u);
                uint_t a23 = __builtin_amdgcn_perm(__float_as_uint(e3), __float_as_uint(e2), 0x07060302u);
                *(uint2*)&Ps[p0 + l15][j4 * 16 + quad * 4] = make_uint2(a01, a23);
            }
        }
        #pragma unroll
        for (int step = 0; step < 2; ++step) {
            bf16x8 bv[4];
            #pragma unroll
            for (int t4 = 0; t4 < 4; ++t4)
                bv[t4] = *(const bf16x8*)&Vs[cur][step][t4 * 16 + l15][(quad ^ rfs) * 8];
            #pragma unroll
            for (int s = 0; s < 2; ++s) {
                int p0 = wave * 32 + s * 16;
                bf16x8 a = *(const bf16x8*)&Ps[p0 + l15][step * 32 + quad * 8];
                #pragma unroll
                for (int t4 = 0; t4 < 4; ++t4)
                    o_acc[s][t4] = MFMA16(bv[t4], a, o_acc[s][t4]);   // swapped: lane=q
            }
        }
    }

    // partial outputs: unnormalized o (f32) + l per (q,h)
    #pragma unroll
    for (int s = 0; s < 2; ++s) {
        float v = l_part[s];
        v += __shfl_xor(v, 16, 64);
        v += __shfl_xor(v, 32, 64);
        int ql = wave * 32 + s * 16 + l15;
        int tok = tile * 128 + ql;
        float* op = Opart + ((size_t)half * 4608 + b * Lh + tok) * Ch + h * 64;
        #pragma unroll
        for (int t4 = 0; t4 < 4; ++t4)
            *(f32x4*)&op[t4 * 16 + quad * 4] = o_acc[s][t4];
        if (quad == 0)
            Lpart[((size_t)half * 4608 + b * Lh + tok) * NHh + h] = v;
    }
}

__device__ __forceinline__ void attn_local_body(
    const ushort_t* __restrict__ QKV, const ushort_t* __restrict__ VT,
    ushort_t* __restrict__ O, int tile, int h, int b,
    ushort_t (*Ks)[2][64][32], ushort_t (*Vs)[2][64][32], ushort_t (*Ps)[72])
{
    int tid = threadIdx.x;
    int lane = tid & 63;
    int wave = tid >> 6;
    int quad = lane >> 4, l15 = lane & 15;
    int wi = tile / 6, wj = tile % 6;

    bf16x8 aq[2];
    {
        int ql = wave * 16 + l15;
        int tok = (wi * 8 + (ql >> 3)) * 48 + wj * 8 + (ql & 7);
        const ushort_t* qbase = QKV + (size_t)(b * Lh + tok) * QS2 + 1536 + h * 64;
        #pragma unroll
        for (int step = 0; step < 2; ++step)
            aq[step] = *(const bf16x8*)(qbase + step * 32 + quad * 8);
    }

    // staging: K rows = window tokens; V rows = d, chunks = token-groups
    {
        int srow = lane >> 2;
        int sc = lane & 3;
        int krow = wave * 16 + srow;
        int kfs = (krow >> 1) & 3;
        int tokK = (wi * 8 + (krow >> 3)) * 48 + wj * 8 + (krow & 7);
        const ushort_t* ksrc = QKV + (size_t)(b * Lh + tokK) * QS2 + 2304 + h * 64 + (sc ^ kfs) * 8;
        int c0 = sc ^ kfs;
        const ushort_t* vbase = VT + (size_t)(768 + h * 64 + krow) * 4608 + b * Lh + wj * 8;
        llds16(&Ks[0][0][wave * 16][0], ksrc);
        llds16(&Ks[0][1][wave * 16][0], ksrc + 32);
        llds16(&Vs[0][0][wave * 16][0], vbase + (wi * 8 + c0) * 48);
        llds16(&Vs[0][1][wave * 16][0], vbase + (wi * 8 + 4 + c0) * 48);
    }
    __syncthreads();

    float l_part = 0.f;
    f32x4 o_acc[4];
    #pragma unroll
    for (int t4 = 0; t4 < 4; ++t4) o_acc[t4] = (f32x4){0.f, 0.f, 0.f, 0.f};

    int rfs = (l15 >> 1) & 3;
    f32x4 s4[4];
    #pragma unroll
    for (int j4 = 0; j4 < 4; ++j4) s4[j4] = (f32x4){0.f, 0.f, 0.f, 0.f};
    #pragma unroll
    for (int step = 0; step < 2; ++step) {
        bf16x8 bk[4];
        #pragma unroll
        for (int j4 = 0; j4 < 4; ++j4)
            bk[j4] = *(const bf16x8*)&Ks[0][step][j4 * 16 + l15][(quad ^ rfs) * 8];
        #pragma unroll
        for (int j4 = 0; j4 < 4; ++j4)
            s4[j4] = MFMA16(bk[j4], aq[step], s4[j4]);
    }
    int p0 = wave * 16;
    #pragma unroll
    for (int j4 = 0; j4 < 4; ++j4) {
        float e0 = EXP2F(s4[j4][0] * SCL2);
        float e1 = EXP2F(s4[j4][1] * SCL2);
        float e2 = EXP2F(s4[j4][2] * SCL2);
        float e3 = EXP2F(s4[j4][3] * SCL2);
        l_part += (e0 + e1) + (e2 + e3);
        uint_t a01 = __builtin_amdgcn_perm(__float_as_uint(e1), __float_as_uint(e0), 0x07060302u);
        uint_t a23 = __builtin_amdgcn_perm(__float_as_uint(e3), __float_as_uint(e2), 0x07060302u);
        *(uint2*)&Ps[p0 + l15][j4 * 16 + quad * 4] = make_uint2(a01, a23);
    }
    #pragma unroll
    for (int step = 0; step < 2; ++step) {
        bf16x8 bv[4];
        #pragma unroll
        for (int t4 = 0; t4 < 4; ++t4)
            bv[t4] = *(const bf16x8*)&Vs[0][step][t4 * 16 + l15][(quad ^ rfs) * 8];
        bf16x8 a = *(const bf16x8*)&Ps[p0 + l15][step * 32 + quad * 8];
        #pragma unroll
        for (int t4 = 0; t4 < 4; ++t4)
            o_acc[t4] = MFMA16(bv[t4], a, o_acc[t4]);   // swapped: lane=q
    }

    {
        float v = l_part;
        v += __shfl_xor(v, 16, 64);
        v += __shfl_xor(v, 32, 64);
        float inv = 1.0f / v;
        int ql = wave * 16 + l15;
        int tok = (wi * 8 + (ql >> 3)) * 48 + wj * 8 + (ql & 7);
        ushort_t* ob = O + (size_t)(b * Lh + tok) * Ch + h * 64;
        #pragma unroll
        for (int t4 = 0; t4 < 4; ++t4) {
            *(uint2*)&ob[t4 * 16 + quad * 4] =
                make_uint2(pack2bf(o_acc[t4][0] * inv, o_acc[t4][1] * inv),
                           pack2bf(o_acc[t4][2] * inv, o_acc[t4][3] * inv));
        }
    }
}

__global__ __launch_bounds__(256)
void attn_fused_kernel(const ushort_t* __restrict__ QKV, const ushort_t* __restrict__ VT,
                       const float* __restrict__ fg,
                       float* __restrict__ Opart, float* __restrict__ Lpart,
                       ushort_t* __restrict__ ctxl)
{
    __shared__ __align__(16) ushort_t Ks[2][2][64][32];
    __shared__ __align__(16) ushort_t Vs[2][2][64][32];
    __shared__ __align__(16) ushort_t Ps[128][72];
    __shared__ float fgs[2][64];

    int bid = blockIdx.x;
    if (bid < 864) {
        // bijective XCD swizzle: 108 consecutive logical blocks per XCD
        int gid = (bid & 7) * 108 + (bid >> 3);
        int half = gid / 432;
        int rem = gid % 432;
        int tile = rem % 18;
        int h = (rem / 18) % NHh;
        int b = rem / 216;
        attn_global_body(QKV, VT, fg, Opart, Lpart, tile, h, b, half, Ks, Vs, Ps, fgs);
    } else {
        int rr = bid - 864;
        int lid = (rr & 7) * 108 + (rr >> 3);
        int tile = lid % 36;
        int h = (lid / 36) % NHh;
        int b = lid / 432;
        attn_local_body(QKV, VT, ctxl, tile, h, b, Ks, Vs, Ps);
    }
}

// ---------------------------------------------------------------- split-KV merge
// ctxg[r][d] = (Oa[r][d] + Ob[r][d]) / (La[r][h] + Lb[r][h]), bf16 out
__global__ __launch_bounds__(192)
void attn_merge_kernel(const float* __restrict__ Op, const float* __restrict__ Lp,
                       ushort_t* __restrict__ ctxg)
{
    int r = blockIdx.x;
    int tid = threadIdx.x;
    int d = tid * 4;
    int h = d >> 6;
    float la = Lp[(size_t)r * NHh + h];
    float lb = Lp[((size_t)4608 + r) * NHh + h];
    float inv = 1.0f / (la + lb);
    const float* pa = Op + (size_t)r * Ch + d;
    const float* pb = Op + (size_t)4608 * Ch + (size_t)r * Ch + d;
    float4 a = *(const float4*)pa;
    float4 b4 = *(const float4*)pb;
    *(uint2*)&ctxg[(size_t)r * Ch + d] =
        make_uint2(pack2bf((a.x + b4.x) * inv, (a.y + b4.y) * inv),
                   pack2bf((a.z + b4.z) * inv, (a.w + b4.w) * inv));
}

// ---------------------------------------------------------------- launch
extern "C" void kernel_launch(void* const* d_in, const int* in_sizes, int n_in,
                              void* d_out, int out_size, void* d_ws, size_t ws_size,
                              hipStream_t stream)
{
    const float* x       = (const float*)d_in[0];
    const float* mask    = (const float*)d_in[1];
    const float* w_qkv_g = (const float*)d_in[2];
    const float* b_qkv_g = (const float*)d_in[3];
    const float* w_o_g   = (const float*)d_in[4];
    const float* b_o_g   = (const float*)d_in[5];
    const float* w_qkv_l = (const float*)d_in[6];
    const float* b_qkv_l = (const float*)d_in[7];
    const float* w_o_l   = (const float*)d_in[8];
    const float* b_o_l   = (const float*)d_in[9];
    const float* ln1_w   = (const float*)d_in[10];
    const float* ln1_b   = (const float*)d_in[11];
    const float* ln2_w   = (const float*)d_in[12];
    const float* ln2_b   = (const float*)d_in[13];
    const float* w_fc1   = (const float*)d_in[14];
    const float* b_fc1   = (const float*)d_in[15];
    const float* w_fc2   = (const float*)d_in[16];
    const float* b_fc2   = (const float*)d_in[17];
    float* out = (float*)d_out;

    const size_t U = (size_t)Bh * Lh * Ch;           // 3,538,944
    char* p = (char*)d_ws;
    ushort_t* qkvb = (ushort_t*)p;        p += (size_t)4608 * 3072 * 2;  // [4608][qg|kg|ql|kl]
    ushort_t* vtb  = (ushort_t*)p;        p += (size_t)1536 * 4608 * 2;  // V^T [col'][token]
    ushort_t* midb = qkvb;                                               // [4608][3072] aliases
    ushort_t* ctxg = (ushort_t*)p;        p += U * 2;
    ushort_t* ctxl = (ushort_t*)p;        p += U * 2;
    ushort_t* xnb  = (ushort_t*)p;        p += U * 2;
    float*    Opart = (float*)p;          p += (size_t)2 * U * 4;        // f32 partials (2 halves)
    float*    Lpart = (float*)p;          p += (size_t)2 * 4608 * NHh * 4;
    float*    x1   = Opart;               // alias: x1 live only after merge consumed Opart
    ushort_t* wtq  = (ushort_t*)p;        p += (size_t)4608 * 768 * 2;   // qkv g|l concat
    ushort_t* wt_o_g = (ushort_t*)p;      p += (size_t)768 * 768 * 2;
    ushort_t* wt_o_l = (ushort_t*)p;      p += (size_t)768 * 768 * 2;
    ushort_t* wt_fc1 = (ushort_t*)p;      p += (size_t)3072 * 768 * 2;
    ushort_t* wt_fc2 = (ushort_t*)p;      p += (size_t)768 * 3072 * 2;
    float*    biasq  = (float*)p;         p += 4608 * 4;
    float*    fg     = (float*)p;         p += Bh * Lh * 4;
    float*    bgw    = (float*)p;

    const int Mrows = Bh * Lh;                   // 4608
    dim3 blk(256);

    // weights + biases (blocks 2304/2305 copy biasq)
    transpose_all_kernel<<<2306, blk, 0, stream>>>(
        w_qkv_g, w_qkv_l, w_o_g, w_o_l, w_fc1, w_fc2, b_qkv_g, b_qkv_l,
        wtq, wt_o_g, wt_o_l, wt_fc1, wt_fc2, biasq);

    // ln1 + mask fused (blocks 4608..4679 do the mask windows)
    ln_mask_kernel<<<4680, blk, 0, stream>>>(x, ln1_w, ln1_b, xnb, mask, fg, bgw);

    // QKV GEMM: one dispatch, bx<24 = Q|K tiles, bx>=24 = V tiles (V^T out)
    qkv_gemm_kernel<<<dim3(36, Mrows / 128), blk, 0, stream>>>(
        xnb, wtq, biasq, qkvb, vtb);

    // fused attention: 864 global split-KV blocks + 864 local blocks
    attn_fused_kernel<<<1728, blk, 0, stream>>>(qkvb, vtb, fg, Opart, Lpart, ctxl);
    attn_merge_kernel<<<Mrows, dim3(192), 0, stream>>>(Opart, Lpart, ctxg);

    // dual masked o-projection -> x1 (one fused dispatch, single K-loop)
    oproj_dual_kernel<<<dim3(Ch / 64, Mrows / 128), blk, 0, stream>>>(
        ctxg, ctxl, wt_o_g, wt_o_l, b_o_g, b_o_l, x, x1, fg, bgw);

    layernorm_bf16_kernel<<<Mrows, blk, 0, stream>>>(x1, ln2_w, ln2_b, xnb);

    // MLP
    gemm_bf16_t<128><<<dim3(3072 / 128, Mrows / 128), blk, 0, stream>>>(
        xnb, wt_fc1, b_fc1, nullptr, midb, Mrows, 3072, Ch, 1 | 2);
    gemm_bf16_t<64><<<dim3(Ch / 64, Mrows / 128), blk, 0, stream>>>(
        midb, wt_fc2, b_fc2, x1, out, Mrows, Ch, 3072, 0);
}